// Round 1
// baseline (9615.791 us; speedup 1.0000x reference)
//
#include <hip/hip_runtime.h>
#include <hip/hip_bf16.h>
#include <cstdint>

static constexpr int D = 128;   // feature dim for all layers (D == H == O == 128)

// ---------------- BN precompute: scale = g*rsqrt(v+eps); shift = (lin_b - m)*scale + b
__global__ void bn_pre_kernel(const float* __restrict__ g, const float* __restrict__ b,
                              const float* __restrict__ m, const float* __restrict__ v,
                              const float* __restrict__ lin_b,
                              float* __restrict__ scale, float* __restrict__ shift) {
    int i = threadIdx.x;
    if (i < D) {
        float s = g[i] * rsqrtf(v[i] + 1e-5f);
        scale[i] = s;
        shift[i] = (lin_b[i] - m[i]) * s + b[i];
    }
}

// ---------------- edge scatter-add: agg[dst] += h[src]
// thread per (edge, float4-quad): 32 threads per edge
__global__ __launch_bounds__(256) void edge_kernel(const float* __restrict__ h,
                                                   float* __restrict__ agg,
                                                   const int* __restrict__ src,
                                                   const int* __restrict__ dst,
                                                   int nE) {
    long long tid = (long long)blockIdx.x * 256 + threadIdx.x;
    int e = (int)(tid >> 5);
    if (e >= nE) return;
    int q = (int)(tid & 31);
    int s = src[e], d = dst[e];
    float4 val = reinterpret_cast<const float4*>(h + (size_t)s * D)[q];
    float* o = agg + (size_t)d * D + q * 4;
    unsafeAtomicAdd(o + 0, val.x);
    unsafeAtomicAdd(o + 1, val.y);
    unsafeAtomicAdd(o + 2, val.z);
    unsafeAtomicAdd(o + 3, val.w);
}

// ---------------- f32 GEMM with fused epilogue
// out[r][c] = epi( sum_k (A[r][k] (+A2[r][k])) * W[k][c] )
// epi: HAS_BN ? relu(acc*scale[c]+shift[c]) : relu(acc + bias[c])
// tile: 32 rows x 64 cols, 256 threads, grid (ceil(N/32), 2)
template<bool HAS_AGG, bool HAS_BN>
__global__ __launch_bounds__(256) void gemm_kernel(
    const float* __restrict__ A, const float* __restrict__ A2,
    const float* __restrict__ W,
    const float* __restrict__ bias,
    const float* __restrict__ bnscale, const float* __restrict__ bnshift,
    float* __restrict__ out, int nN) {
    __shared__ float Wl[D * 64];     // 32 KB: W[:, c0:c0+64]
    __shared__ float Al[32 * D];     // 16 KB: A tile (+agg)
    __shared__ float epA[64];
    __shared__ float epB[64];

    int tid = threadIdx.x;
    int row0 = blockIdx.x * 32;
    int c0 = blockIdx.y * 64;

    // stage W columns [c0, c0+64)
    const float4* W4 = reinterpret_cast<const float4*>(W);
    float4* Wl4 = reinterpret_cast<float4*>(Wl);
    int c0q = c0 >> 2;
    for (int i = tid; i < D * 16; i += 256) {
        int k = i >> 4, j = i & 15;
        Wl4[i] = W4[k * (D / 4) + c0q + j];
    }
    if (tid < 64) {
        if (HAS_BN) { epA[tid] = bnscale[c0 + tid]; epB[tid] = bnshift[c0 + tid]; }
        else        { epA[tid] = bias[c0 + tid]; }
    }
    // stage A tile (optionally + A2)
    const float4* A4  = reinterpret_cast<const float4*>(A);
    const float4* A24 = reinterpret_cast<const float4*>(A2);
    float4* Al4 = reinterpret_cast<float4*>(Al);
    for (int i = tid; i < 32 * (D / 4); i += 256) {
        int r = i >> 5;           // D/4 == 32 quads per row
        int grow = row0 + r;
        float4 v;
        if (grow < nN) {
            v = A4[(size_t)grow * (D / 4) + (i & 31)];
            if (HAS_AGG) {
                float4 g = A24[(size_t)grow * (D / 4) + (i & 31)];
                v.x += g.x; v.y += g.y; v.z += g.z; v.w += g.w;
            }
        } else {
            v = make_float4(0.f, 0.f, 0.f, 0.f);
        }
        Al4[i] = v;
    }
    __syncthreads();

    int cq = (tid & 15) * 4;      // local col base (0..60)
    int rg = (tid >> 4) * 2;      // local row base (0..30)
    float acc[2][4] = {};

#pragma unroll 8
    for (int k = 0; k < D; ++k) {
        float4 w = *reinterpret_cast<const float4*>(&Wl[k * 64 + cq]);
        float a0 = Al[(rg + 0) * D + k];
        float a1 = Al[(rg + 1) * D + k];
        acc[0][0] = fmaf(a0, w.x, acc[0][0]); acc[0][1] = fmaf(a0, w.y, acc[0][1]);
        acc[0][2] = fmaf(a0, w.z, acc[0][2]); acc[0][3] = fmaf(a0, w.w, acc[0][3]);
        acc[1][0] = fmaf(a1, w.x, acc[1][0]); acc[1][1] = fmaf(a1, w.y, acc[1][1]);
        acc[1][2] = fmaf(a1, w.z, acc[1][2]); acc[1][3] = fmaf(a1, w.w, acc[1][3]);
    }

#pragma unroll
    for (int i = 0; i < 2; ++i) {
        int grow = row0 + rg + i;
        if (grow >= nN) continue;
        float4 o;
        if (HAS_BN) {
            o.x = fmaxf(acc[i][0] * epA[cq + 0] + epB[cq + 0], 0.f);
            o.y = fmaxf(acc[i][1] * epA[cq + 1] + epB[cq + 1], 0.f);
            o.z = fmaxf(acc[i][2] * epA[cq + 2] + epB[cq + 2], 0.f);
            o.w = fmaxf(acc[i][3] * epA[cq + 3] + epB[cq + 3], 0.f);
        } else {
            o.x = fmaxf(acc[i][0] + epA[cq + 0], 0.f);
            o.y = fmaxf(acc[i][1] + epA[cq + 1], 0.f);
            o.z = fmaxf(acc[i][2] + epA[cq + 2], 0.f);
            o.w = fmaxf(acc[i][3] + epA[cq + 3], 0.f);
        }
        *reinterpret_cast<float4*>(out + (size_t)grow * D + c0 + cq) = o;
    }
}

// ---------------- pooling
__global__ void zero_kernel(float* __restrict__ out, int n, int* __restrict__ cnt, int ncnt) {
    int i = blockIdx.x * 256 + threadIdx.x;
    if (i < n) out[i] = 0.f;
    if (i < ncnt) cnt[i] = 0;
}

__global__ __launch_bounds__(256) void count_kernel(const int* __restrict__ batch,
                                                    int* __restrict__ cnt, int n) {
    int i = blockIdx.x * 256 + threadIdx.x;
    if (i < n) atomicAdd(&cnt[batch[i]], 1);
}

__global__ __launch_bounds__(256) void pool_kernel(const float* __restrict__ h,
                                                   const int* __restrict__ batch,
                                                   float* __restrict__ out, int n) {
    long long tid = (long long)blockIdx.x * 256 + threadIdx.x;
    int i = (int)(tid >> 5);
    if (i >= n) return;
    int q = (int)(tid & 31);
    int g = batch[i];
    float4 v = reinterpret_cast<const float4*>(h + (size_t)i * D)[q];
    float* o = out + (size_t)g * D + q * 4;
    unsafeAtomicAdd(o + 0, v.x);
    unsafeAtomicAdd(o + 1, v.y);
    unsafeAtomicAdd(o + 2, v.z);
    unsafeAtomicAdd(o + 3, v.w);
}

__global__ void div_kernel(float* __restrict__ out, const int* __restrict__ cnt, int n) {
    int i = blockIdx.x * 256 + threadIdx.x;
    if (i < n) out[i] /= fmaxf((float)cnt[i >> 7], 1.f);
}

extern "C" void kernel_launch(void* const* d_in, const int* in_sizes, int n_in,
                              void* d_out, int out_size, void* d_ws, size_t ws_size,
                              hipStream_t stream) {
    const float* x    = (const float*)d_in[0];
    const int*   ei   = (const int*)d_in[1];
    const int*   batch= (const int*)d_in[2];
    const float* w11 = (const float*)d_in[3];  const float* b11 = (const float*)d_in[4];
    const float* w12 = (const float*)d_in[5];  const float* b12 = (const float*)d_in[6];
    const float* w21 = (const float*)d_in[7];  const float* b21 = (const float*)d_in[8];
    const float* w22 = (const float*)d_in[9];  const float* b22 = (const float*)d_in[10];
    const float* w31 = (const float*)d_in[11]; const float* b31 = (const float*)d_in[12];
    const float* w32 = (const float*)d_in[13]; const float* b32 = (const float*)d_in[14];
    const float* bn1g = (const float*)d_in[15]; const float* bn1b = (const float*)d_in[16];
    const float* bn1m = (const float*)d_in[17]; const float* bn1v = (const float*)d_in[18];
    const float* bn2g = (const float*)d_in[19]; const float* bn2b = (const float*)d_in[20];
    const float* bn2m = (const float*)d_in[21]; const float* bn2v = (const float*)d_in[22];
    const float* bn3g = (const float*)d_in[23]; const float* bn3b = (const float*)d_in[24];
    const float* bn3m = (const float*)d_in[25]; const float* bn3v = (const float*)d_in[26];

    int nN = in_sizes[0] / D;
    int nE = in_sizes[1] / 2;
    int nG = out_size / D;

    const int* srcp = ei;
    const int* dstp = ei + nE;

    size_t NB = (size_t)nN * D * sizeof(float);
    char* ws = (char*)d_ws;
    float* S = (float*)ws;             // aggregation buffer
    float* M = (float*)(ws + NB);      // MLP mid
    float* P = (float*)(ws + 2 * NB);  // layer features
    float* aux = (float*)(ws + 3 * NB);
    float* sc1 = aux + 0,   *sh1 = aux + 128;
    float* sc2 = aux + 256, *sh2 = aux + 384;
    float* sc3 = aux + 512, *sh3 = aux + 640;
    int*   cnt = (int*)(aux + 768);

    bn_pre_kernel<<<1, 128, 0, stream>>>(bn1g, bn1b, bn1m, bn1v, b12, sc1, sh1);
    bn_pre_kernel<<<1, 128, 0, stream>>>(bn2g, bn2b, bn2m, bn2v, b22, sc2, sh2);
    bn_pre_kernel<<<1, 128, 0, stream>>>(bn3g, bn3b, bn3m, bn3v, b32, sc3, sh3);

    dim3 gGemm((nN + 31) / 32, 2);
    int edgeBlocks = (int)(((long long)nE * 32 + 255) / 256);

    // ---- layer 1
    hipMemsetAsync(S, 0, NB, stream);
    edge_kernel<<<edgeBlocks, 256, 0, stream>>>(x, S, srcp, dstp, nE);
    gemm_kernel<true, false><<<gGemm, 256, 0, stream>>>(x, S, w11, b11, nullptr, nullptr, M, nN);
    gemm_kernel<false, true><<<gGemm, 256, 0, stream>>>(M, nullptr, w12, nullptr, sc1, sh1, P, nN);

    // ---- layer 2
    hipMemsetAsync(S, 0, NB, stream);
    edge_kernel<<<edgeBlocks, 256, 0, stream>>>(P, S, srcp, dstp, nE);
    gemm_kernel<true, false><<<gGemm, 256, 0, stream>>>(P, S, w21, b21, nullptr, nullptr, M, nN);
    gemm_kernel<false, true><<<gGemm, 256, 0, stream>>>(M, nullptr, w22, nullptr, sc2, sh2, P, nN);

    // ---- layer 3
    hipMemsetAsync(S, 0, NB, stream);
    edge_kernel<<<edgeBlocks, 256, 0, stream>>>(P, S, srcp, dstp, nE);
    gemm_kernel<true, false><<<gGemm, 256, 0, stream>>>(P, S, w31, b31, nullptr, nullptr, M, nN);
    gemm_kernel<false, true><<<gGemm, 256, 0, stream>>>(M, nullptr, w32, nullptr, sc3, sh3, P, nN);

    // ---- global mean pool
    zero_kernel<<<(nG * D + 255) / 256, 256, 0, stream>>>((float*)d_out, nG * D, cnt, nG);
    count_kernel<<<(nN + 255) / 256, 256, 0, stream>>>(batch, cnt, nN);
    pool_kernel<<<(int)(((long long)nN * 32 + 255) / 256), 256, 0, stream>>>(P, batch, (float*)d_out, nN);
    div_kernel<<<(nG * D + 255) / 256, 256, 0, stream>>>((float*)d_out, cnt, nG * D);
}

// Round 2
// 1598.388 us; speedup vs baseline: 6.0159x; 6.0159x over previous
//
#include <hip/hip_runtime.h>
#include <hip/hip_bf16.h>
#include <cstdint>

static constexpr int D = 128;   // feature dim for all layers (D == H == O == 128)

// ---------------- BN precompute: scale = g*rsqrt(v+eps); shift = (lin_b - m)*scale + b
__global__ void bn_pre_kernel(const float* __restrict__ g, const float* __restrict__ b,
                              const float* __restrict__ m, const float* __restrict__ v,
                              const float* __restrict__ lin_b,
                              float* __restrict__ scale, float* __restrict__ shift) {
    int i = threadIdx.x;
    if (i < D) {
        float s = g[i] * rsqrtf(v[i] + 1e-5f);
        scale[i] = s;
        shift[i] = (lin_b[i] - m[i]) * s + b[i];
    }
}

// ---------------- CSR build ----------------
__global__ void zero_int_kernel(int* __restrict__ p, int n) {
    int i = blockIdx.x * 256 + threadIdx.x;
    if (i < n) p[i] = 0;
}

__global__ __launch_bounds__(256) void count_deg_kernel(const int* __restrict__ dst,
                                                        int* __restrict__ cnt, int nE) {
    int e = blockIdx.x * 256 + threadIdx.x;
    if (e < nE) atomicAdd(&cnt[dst[e]], 1);
}

// per-block exclusive scan (256 elems), block sums out
__global__ __launch_bounds__(256) void scan1_kernel(const int* __restrict__ cnt,
                                                    int* __restrict__ rowptr,
                                                    int* __restrict__ bsum, int n) {
    __shared__ int s[256];
    int t = threadIdx.x;
    int i = blockIdx.x * 256 + t;
    int v = (i < n) ? cnt[i] : 0;
    s[t] = v;
    __syncthreads();
#pragma unroll
    for (int off = 1; off < 256; off <<= 1) {
        int add = (t >= off) ? s[t - off] : 0;
        __syncthreads();
        s[t] += add;
        __syncthreads();
    }
    if (i < n) rowptr[i] = s[t] - v;     // exclusive within block
    if (t == 255) bsum[blockIdx.x] = s[255];
}

// serial scan of block sums (nb ~ 391, trivial)
__global__ void scan2_kernel(int* __restrict__ bsum, int nb) {
    if (threadIdx.x == 0) {
        int run = 0;
        for (int b = 0; b < nb; ++b) { int t = bsum[b]; bsum[b] = run; run += t; }
        bsum[nb] = run;
    }
}

__global__ __launch_bounds__(256) void scan3_kernel(int* __restrict__ rowptr,
                                                    int* __restrict__ cursor,
                                                    const int* __restrict__ bsum,
                                                    int n, int nb) {
    int i = blockIdx.x * 256 + threadIdx.x;
    if (i < n) {
        int v = rowptr[i] + bsum[blockIdx.x];
        rowptr[i] = v;
        cursor[i] = v;
    }
    if (blockIdx.x == 0 && threadIdx.x == 0) rowptr[n] = bsum[nb];
}

__global__ __launch_bounds__(256) void fill_kernel(const int* __restrict__ src,
                                                   const int* __restrict__ dst,
                                                   int* __restrict__ cursor,
                                                   int* __restrict__ col, int nE) {
    int e = blockIdx.x * 256 + threadIdx.x;
    if (e < nE) {
        int p = atomicAdd(&cursor[dst[e]], 1);
        col[p] = src[e];
    }
}

// ---------------- gather aggregation: S[i] = h[i] + sum_{j in nbrs(i)} h[j]
// 32 lanes per node (one float4 quad per lane), 8 nodes per block
__global__ __launch_bounds__(256) void agg_kernel(const float* __restrict__ h,
                                                  float* __restrict__ S,
                                                  const int* __restrict__ rowptr,
                                                  const int* __restrict__ col, int nN) {
    int node = blockIdx.x * 8 + (threadIdx.x >> 5);
    if (node >= nN) return;
    int q = threadIdx.x & 31;
    const float4* h4 = reinterpret_cast<const float4*>(h);
    float4 acc = h4[(size_t)node * 32 + q];      // self term
    int beg = rowptr[node], end = rowptr[node + 1];
    for (int j = beg; j < end; ++j) {
        int s = col[j];                           // broadcast within 32-lane group
        float4 v = h4[(size_t)s * 32 + q];
        acc.x += v.x; acc.y += v.y; acc.z += v.z; acc.w += v.w;
    }
    reinterpret_cast<float4*>(S)[(size_t)node * 32 + q] = acc;
}

// ---------------- f32 GEMM with fused epilogue
// out[r][c] = epi( sum_k A[r][k] * W[k][c] )
// epi: HAS_BN ? relu(acc*scale[c]+shift[c]) : relu(acc + bias[c])
template<bool HAS_BN>
__global__ __launch_bounds__(256) void gemm_kernel(
    const float* __restrict__ A,
    const float* __restrict__ W,
    const float* __restrict__ bias,
    const float* __restrict__ bnscale, const float* __restrict__ bnshift,
    float* __restrict__ out, int nN) {
    __shared__ float Wl[D * 64];     // 32 KB: W[:, c0:c0+64]
    __shared__ float Al[32 * D];     // 16 KB: A tile
    __shared__ float epA[64];
    __shared__ float epB[64];

    int tid = threadIdx.x;
    int row0 = blockIdx.x * 32;
    int c0 = blockIdx.y * 64;

    const float4* W4 = reinterpret_cast<const float4*>(W);
    float4* Wl4 = reinterpret_cast<float4*>(Wl);
    int c0q = c0 >> 2;
    for (int i = tid; i < D * 16; i += 256) {
        int k = i >> 4, j = i & 15;
        Wl4[i] = W4[k * (D / 4) + c0q + j];
    }
    if (tid < 64) {
        if (HAS_BN) { epA[tid] = bnscale[c0 + tid]; epB[tid] = bnshift[c0 + tid]; }
        else        { epA[tid] = bias[c0 + tid]; }
    }
    const float4* A4 = reinterpret_cast<const float4*>(A);
    float4* Al4 = reinterpret_cast<float4*>(Al);
    for (int i = tid; i < 32 * (D / 4); i += 256) {
        int grow = row0 + (i >> 5);
        Al4[i] = (grow < nN) ? A4[(size_t)grow * (D / 4) + (i & 31)]
                             : make_float4(0.f, 0.f, 0.f, 0.f);
    }
    __syncthreads();

    int cq = (tid & 15) * 4;      // local col base (0..60)
    int rg = (tid >> 4) * 2;      // local row base (0..30)
    float acc[2][4] = {};

#pragma unroll 8
    for (int k = 0; k < D; ++k) {
        float4 w = *reinterpret_cast<const float4*>(&Wl[k * 64 + cq]);
        float a0 = Al[(rg + 0) * D + k];
        float a1 = Al[(rg + 1) * D + k];
        acc[0][0] = fmaf(a0, w.x, acc[0][0]); acc[0][1] = fmaf(a0, w.y, acc[0][1]);
        acc[0][2] = fmaf(a0, w.z, acc[0][2]); acc[0][3] = fmaf(a0, w.w, acc[0][3]);
        acc[1][0] = fmaf(a1, w.x, acc[1][0]); acc[1][1] = fmaf(a1, w.y, acc[1][1]);
        acc[1][2] = fmaf(a1, w.z, acc[1][2]); acc[1][3] = fmaf(a1, w.w, acc[1][3]);
    }

#pragma unroll
    for (int i = 0; i < 2; ++i) {
        int grow = row0 + rg + i;
        if (grow >= nN) continue;
        float4 o;
        if (HAS_BN) {
            o.x = fmaxf(acc[i][0] * epA[cq + 0] + epB[cq + 0], 0.f);
            o.y = fmaxf(acc[i][1] * epA[cq + 1] + epB[cq + 1], 0.f);
            o.z = fmaxf(acc[i][2] * epA[cq + 2] + epB[cq + 2], 0.f);
            o.w = fmaxf(acc[i][3] * epA[cq + 3] + epB[cq + 3], 0.f);
        } else {
            o.x = fmaxf(acc[i][0] + epA[cq + 0], 0.f);
            o.y = fmaxf(acc[i][1] + epA[cq + 1], 0.f);
            o.z = fmaxf(acc[i][2] + epA[cq + 2], 0.f);
            o.w = fmaxf(acc[i][3] + epA[cq + 3], 0.f);
        }
        *reinterpret_cast<float4*>(out + (size_t)grow * D + c0 + cq) = o;
    }
}

// ---------------- pooling
__global__ void zero_kernel(float* __restrict__ out, int n, int* __restrict__ cnt, int ncnt) {
    int i = blockIdx.x * 256 + threadIdx.x;
    if (i < n) out[i] = 0.f;
    if (i < ncnt) cnt[i] = 0;
}

__global__ __launch_bounds__(256) void count_kernel(const int* __restrict__ batch,
                                                    int* __restrict__ cnt, int n) {
    int i = blockIdx.x * 256 + threadIdx.x;
    if (i < n) atomicAdd(&cnt[batch[i]], 1);
}

// batch is sorted: run-length accumulate, flush at graph boundary
__global__ __launch_bounds__(256) void pool_kernel(const float* __restrict__ h,
                                                   const int* __restrict__ batch,
                                                   float* __restrict__ out, int nN, int span) {
    int grp = blockIdx.x * 8 + (threadIdx.x >> 5);
    int q = threadIdx.x & 31;
    int beg = grp * span;
    if (beg >= nN) return;
    int end = min(beg + span, nN);
    const float4* h4 = reinterpret_cast<const float4*>(h);
    int curg = batch[beg];
    float4 acc = make_float4(0.f, 0.f, 0.f, 0.f);
    for (int i = beg; i < end; ++i) {
        int g = batch[i];
        if (g != curg) {
            float* o = out + (size_t)curg * D + q * 4;
            unsafeAtomicAdd(o + 0, acc.x);
            unsafeAtomicAdd(o + 1, acc.y);
            unsafeAtomicAdd(o + 2, acc.z);
            unsafeAtomicAdd(o + 3, acc.w);
            acc = make_float4(0.f, 0.f, 0.f, 0.f);
            curg = g;
        }
        float4 v = h4[(size_t)i * 32 + q];
        acc.x += v.x; acc.y += v.y; acc.z += v.z; acc.w += v.w;
    }
    float* o = out + (size_t)curg * D + q * 4;
    unsafeAtomicAdd(o + 0, acc.x);
    unsafeAtomicAdd(o + 1, acc.y);
    unsafeAtomicAdd(o + 2, acc.z);
    unsafeAtomicAdd(o + 3, acc.w);
}

__global__ void div_kernel(float* __restrict__ out, const int* __restrict__ cnt, int n) {
    int i = blockIdx.x * 256 + threadIdx.x;
    if (i < n) out[i] /= fmaxf((float)cnt[i >> 7], 1.f);
}

extern "C" void kernel_launch(void* const* d_in, const int* in_sizes, int n_in,
                              void* d_out, int out_size, void* d_ws, size_t ws_size,
                              hipStream_t stream) {
    const float* x    = (const float*)d_in[0];
    const int*   ei   = (const int*)d_in[1];
    const int*   batch= (const int*)d_in[2];
    const float* w11 = (const float*)d_in[3];  const float* b11 = (const float*)d_in[4];
    const float* w12 = (const float*)d_in[5];  // b12 folded into BN shift
    const float* b12 = (const float*)d_in[6];
    const float* w21 = (const float*)d_in[7];  const float* b21 = (const float*)d_in[8];
    const float* w22 = (const float*)d_in[9];  const float* b22 = (const float*)d_in[10];
    const float* w31 = (const float*)d_in[11]; const float* b31 = (const float*)d_in[12];
    const float* w32 = (const float*)d_in[13]; const float* b32 = (const float*)d_in[14];
    const float* bn1g = (const float*)d_in[15]; const float* bn1b = (const float*)d_in[16];
    const float* bn1m = (const float*)d_in[17]; const float* bn1v = (const float*)d_in[18];
    const float* bn2g = (const float*)d_in[19]; const float* bn2b = (const float*)d_in[20];
    const float* bn2m = (const float*)d_in[21]; const float* bn2v = (const float*)d_in[22];
    const float* bn3g = (const float*)d_in[23]; const float* bn3b = (const float*)d_in[24];
    const float* bn3m = (const float*)d_in[25]; const float* bn3v = (const float*)d_in[26];

    int nN = in_sizes[0] / D;
    int nE = in_sizes[1] / 2;
    int nG = out_size / D;

    const int* srcp = ei;
    const int* dstp = ei + nE;

    size_t NB = (size_t)nN * D * sizeof(float);
    char* ws = (char*)d_ws;
    float* S = (float*)ws;             // aggregated features (self + neighbors)
    float* M = (float*)(ws + NB);      // MLP mid
    float* P = (float*)(ws + 2 * NB);  // layer output features
    float* aux = (float*)(ws + 3 * NB);
    float* sc1 = aux + 0,   *sh1 = aux + 128;
    float* sc2 = aux + 256, *sh2 = aux + 384;
    float* sc3 = aux + 512, *sh3 = aux + 640;
    int*   cnt = (int*)(aux + 768);
    size_t aux_bytes = 4096;

    int nb = (nN + 255) / 256;
    size_t csr_bytes = ((size_t)(nN + 1) + (size_t)nN + (size_t)nE + (size_t)(nb + 1)) * sizeof(int);
    char* csr_base;
    bool per_layer_build;
    if (3 * NB + aux_bytes + csr_bytes <= ws_size) {
        csr_base = ws + 3 * NB + aux_bytes;   // persistent CSR, build once
        per_layer_build = false;
    } else {
        csr_base = (char*)M;                  // overlay on M (dead during agg), rebuild per layer
        per_layer_build = true;
    }
    int* rowptr = (int*)csr_base;
    int* cursor = rowptr + (nN + 1);
    int* col    = cursor + nN;
    int* bsum   = col + nE;

    int eb = (nE + 255) / 256;
    auto build_csr = [&]() {
        zero_int_kernel<<<nb, 256, 0, stream>>>(cursor, nN);
        count_deg_kernel<<<eb, 256, 0, stream>>>(dstp, cursor, nE);
        scan1_kernel<<<nb, 256, 0, stream>>>(cursor, rowptr, bsum, nN);
        scan2_kernel<<<1, 64, 0, stream>>>(bsum, nb);
        scan3_kernel<<<nb, 256, 0, stream>>>(rowptr, cursor, bsum, nN, nb);
        fill_kernel<<<eb, 256, 0, stream>>>(srcp, dstp, cursor, col, nE);
    };

    bn_pre_kernel<<<1, 128, 0, stream>>>(bn1g, bn1b, bn1m, bn1v, b12, sc1, sh1);
    bn_pre_kernel<<<1, 128, 0, stream>>>(bn2g, bn2b, bn2m, bn2v, b22, sc2, sh2);
    bn_pre_kernel<<<1, 128, 0, stream>>>(bn3g, bn3b, bn3m, bn3v, b32, sc3, sh3);

    if (!per_layer_build) build_csr();

    dim3 gGemm((nN + 31) / 32, 2);
    int aggBlocks = (nN + 7) / 8;

    // ---- layer 1
    if (per_layer_build) build_csr();
    agg_kernel<<<aggBlocks, 256, 0, stream>>>(x, S, rowptr, col, nN);
    gemm_kernel<false><<<gGemm, 256, 0, stream>>>(S, w11, b11, nullptr, nullptr, M, nN);
    gemm_kernel<true><<<gGemm, 256, 0, stream>>>(M, w12, nullptr, sc1, sh1, P, nN);

    // ---- layer 2
    if (per_layer_build) build_csr();
    agg_kernel<<<aggBlocks, 256, 0, stream>>>(P, S, rowptr, col, nN);
    gemm_kernel<false><<<gGemm, 256, 0, stream>>>(S, w21, b21, nullptr, nullptr, M, nN);
    gemm_kernel<true><<<gGemm, 256, 0, stream>>>(M, w22, nullptr, sc2, sh2, P, nN);

    // ---- layer 3
    if (per_layer_build) build_csr();
    agg_kernel<<<aggBlocks, 256, 0, stream>>>(P, S, rowptr, col, nN);
    gemm_kernel<false><<<gGemm, 256, 0, stream>>>(S, w31, b31, nullptr, nullptr, M, nN);
    gemm_kernel<true><<<gGemm, 256, 0, stream>>>(M, w32, nullptr, sc3, sh3, P, nN);

    // ---- global mean pool
    zero_kernel<<<(nG * D + 255) / 256, 256, 0, stream>>>((float*)d_out, nG * D, cnt, nG);
    count_kernel<<<(nN + 255) / 256, 256, 0, stream>>>(batch, cnt, nN);
    int span = (nN + 4095) / 4096;
    int ngrp = (nN + span - 1) / span;
    pool_kernel<<<(ngrp + 7) / 8, 256, 0, stream>>>(P, batch, (float*)d_out, nN, span);
    div_kernel<<<(nG * D + 255) / 256, 256, 0, stream>>>((float*)d_out, cnt, nG * D);
}

// Round 3
// 650.973 us; speedup vs baseline: 14.7714x; 2.4554x over previous
//
#include <hip/hip_runtime.h>
#include <hip/hip_bf16.h>
#include <cstdint>

static constexpr int D = 128;   // feature dim for all layers (D == H == O == 128)

typedef __bf16 v8bf __attribute__((ext_vector_type(8)));
typedef float  v4f  __attribute__((ext_vector_type(4)));

__device__ inline float bflo(unsigned u) { return __uint_as_float(u << 16); }
__device__ inline float bfhi(unsigned u) { return __uint_as_float(u & 0xffff0000u); }
__device__ inline unsigned short bfbits(float f) {
    __hip_bfloat16 h = __float2bfloat16(f);
    return *reinterpret_cast<unsigned short*>(&h);
}
__device__ inline unsigned packbf(float a, float b) {
    return (unsigned)bfbits(a) | ((unsigned)bfbits(b) << 16);
}

// ---------------- BN precompute: scale = g*rsqrt(v+eps); shift = (lin_b - m)*scale + b
__global__ void bn_pre_kernel(const float* __restrict__ g, const float* __restrict__ b,
                              const float* __restrict__ m, const float* __restrict__ v,
                              const float* __restrict__ lin_b,
                              float* __restrict__ scale, float* __restrict__ shift) {
    int i = threadIdx.x;
    if (i < D) {
        float s = g[i] * rsqrtf(v[i] + 1e-5f);
        scale[i] = s;
        shift[i] = (lin_b[i] - m[i]) * s + b[i];
    }
}

// ---------------- f32 -> bf16 convert (8 elems / thread)
__global__ __launch_bounds__(256) void cvt_kernel(const float* __restrict__ in,
                                                  __hip_bfloat16* __restrict__ ob,
                                                  long long n8) {
    long long i = (long long)blockIdx.x * 256 + threadIdx.x;
    if (i >= n8) return;
    const float4* f4 = reinterpret_cast<const float4*>(in);
    float4 a = f4[i * 2], b = f4[i * 2 + 1];
    uint4 o = make_uint4(packbf(a.x, a.y), packbf(a.z, a.w),
                         packbf(b.x, b.y), packbf(b.z, b.w));
    reinterpret_cast<uint4*>(ob)[i] = o;
}

// ---------------- weight repack: Wp[w][ks][cf][lane][j] = bf16(W[ks*32+(l>>4)*8+j][cf*16+(l&15)])
__global__ __launch_bounds__(256) void pack_w_kernel(const float* w0, const float* w1,
                                                     const float* w2, const float* w3,
                                                     const float* w4, const float* w5,
                                                     __hip_bfloat16* __restrict__ Wp) {
    int idx = blockIdx.x * 256 + threadIdx.x;
    if (idx >= 6 * 2048) return;
    int widx = idx >> 11, r = idx & 2047;
    const float* W = widx == 0 ? w0 : widx == 1 ? w1 : widx == 2 ? w2
                   : widx == 3 ? w3 : widx == 4 ? w4 : w5;
    int l = r & 63, cf = (r >> 6) & 7, ks = r >> 9;
    int k0 = ks * 32 + (l >> 4) * 8, c = cf * 16 + (l & 15);
    unsigned o0 = packbf(W[(k0 + 0) * D + c], W[(k0 + 1) * D + c]);
    unsigned o1 = packbf(W[(k0 + 2) * D + c], W[(k0 + 3) * D + c]);
    unsigned o2 = packbf(W[(k0 + 4) * D + c], W[(k0 + 5) * D + c]);
    unsigned o3 = packbf(W[(k0 + 6) * D + c], W[(k0 + 7) * D + c]);
    reinterpret_cast<uint4*>(Wp + (size_t)idx * 8)[0] = make_uint4(o0, o1, o2, o3);
}

// ---------------- CSR build ----------------
__global__ void zero_int_kernel(int* __restrict__ p, int n) {
    int i = blockIdx.x * 256 + threadIdx.x;
    if (i < n) p[i] = 0;
}

__global__ __launch_bounds__(256) void count_deg_kernel(const int* __restrict__ dst,
                                                        int* __restrict__ cnt, int nE) {
    int e = blockIdx.x * 256 + threadIdx.x;
    if (e < nE) atomicAdd(&cnt[dst[e]], 1);
}

__global__ __launch_bounds__(256) void scan1_kernel(const int* __restrict__ cnt,
                                                    int* __restrict__ rowptr,
                                                    int* __restrict__ bsum, int n) {
    __shared__ int s[256];
    int t = threadIdx.x;
    int i = blockIdx.x * 256 + t;
    int v = (i < n) ? cnt[i] : 0;
    s[t] = v;
    __syncthreads();
#pragma unroll
    for (int off = 1; off < 256; off <<= 1) {
        int add = (t >= off) ? s[t - off] : 0;
        __syncthreads();
        s[t] += add;
        __syncthreads();
    }
    if (i < n) rowptr[i] = s[t] - v;
    if (t == 255) bsum[blockIdx.x] = s[255];
}

__global__ void scan2_kernel(int* __restrict__ bsum, int nb) {
    if (threadIdx.x == 0) {
        int run = 0;
        for (int b = 0; b < nb; ++b) { int t = bsum[b]; bsum[b] = run; run += t; }
        bsum[nb] = run;
    }
}

__global__ __launch_bounds__(256) void scan3_kernel(int* __restrict__ rowptr,
                                                    int* __restrict__ cursor,
                                                    const int* __restrict__ bsum,
                                                    int n, int nb) {
    int i = blockIdx.x * 256 + threadIdx.x;
    if (i < n) {
        int v = rowptr[i] + bsum[blockIdx.x];
        rowptr[i] = v;
        cursor[i] = v;
    }
    if (blockIdx.x == 0 && threadIdx.x == 0) rowptr[n] = bsum[nb];
}

__global__ __launch_bounds__(256) void fill_kernel(const int* __restrict__ src,
                                                   const int* __restrict__ dst,
                                                   int* __restrict__ cursor,
                                                   int* __restrict__ col, int nE) {
    int e = blockIdx.x * 256 + threadIdx.x;
    if (e < nE) {
        int p = atomicAdd(&cursor[dst[e]], 1);
        col[p] = src[e];
    }
}

// ---------------- gather aggregation (bf16): S[i] = h[i] + sum_{j in nbrs(i)} h[j]
// 16 lanes per node (16B chunk each), 16 nodes per block
__global__ __launch_bounds__(256) void agg_kernel(const __hip_bfloat16* __restrict__ h,
                                                  __hip_bfloat16* __restrict__ S,
                                                  const int* __restrict__ rowptr,
                                                  const int* __restrict__ col, int nN) {
    int node = blockIdx.x * 16 + (threadIdx.x >> 4);
    if (node >= nN) return;
    int q = threadIdx.x & 15;
    const uint4* h4 = reinterpret_cast<const uint4*>(h);
    uint4 u = h4[(size_t)node * 16 + q];
    float a[8];
    a[0] = bflo(u.x); a[1] = bfhi(u.x); a[2] = bflo(u.y); a[3] = bfhi(u.y);
    a[4] = bflo(u.z); a[5] = bfhi(u.z); a[6] = bflo(u.w); a[7] = bfhi(u.w);
    int beg = rowptr[node], end = rowptr[node + 1];
    for (int j = beg; j < end; ++j) {
        int s = col[j];
        uint4 v = h4[(size_t)s * 16 + q];
        a[0] += bflo(v.x); a[1] += bfhi(v.x); a[2] += bflo(v.y); a[3] += bfhi(v.y);
        a[4] += bflo(v.z); a[5] += bfhi(v.z); a[6] += bflo(v.w); a[7] += bfhi(v.w);
    }
    uint4 o = make_uint4(packbf(a[0], a[1]), packbf(a[2], a[3]),
                         packbf(a[4], a[5]), packbf(a[6], a[7]));
    reinterpret_cast<uint4*>(S)[(size_t)node * 16 + q] = o;
}

// ---------------- MFMA GEMM (bf16 in, bf16 out, f32 accum) with fused epilogue
// out[N][128] = epi(A[N][128] @ W[128][128]); W pre-packed fragment-contiguous.
// block = 256 thr = 4 waves; wave w: rows [bid*64 + w*16, +16), all 128 cols.
template<bool HAS_BN>
__global__ __launch_bounds__(256) void gemm_mfma_kernel(
    const __hip_bfloat16* __restrict__ A,
    const __hip_bfloat16* __restrict__ Wp,
    const float* __restrict__ ep0, const float* __restrict__ ep1,
    __hip_bfloat16* __restrict__ out, int nN) {
    int w = threadIdx.x >> 6;
    int l = threadIdx.x & 63;
    int row0 = blockIdx.x * 64 + w * 16;
    int ar = row0 + (l & 15);
    if (ar >= nN) ar = nN - 1;                 // clamp; results discarded on store
    const v8bf* Arow = reinterpret_cast<const v8bf*>(A + (size_t)ar * D);
    const v8bf* Wv = reinterpret_cast<const v8bf*>(Wp);
    int kq = l >> 4;                            // k-quarter within 32-k step

    v4f acc[8] = {};
#pragma unroll
    for (int ks = 0; ks < 4; ++ks) {
        v8bf a = Arow[ks * 4 + kq];
#pragma unroll
        for (int cf = 0; cf < 8; ++cf) {
            v8bf b = Wv[(ks * 8 + cf) * 64 + l];
            acc[cf] = __builtin_amdgcn_mfma_f32_16x16x32_bf16(a, b, acc[cf], 0, 0, 0);
        }
    }

    int rbase = row0 + kq * 4;
#pragma unroll
    for (int cf = 0; cf < 8; ++cf) {
        int c = cf * 16 + (l & 15);
        float p0 = ep0[c];
        float p1 = 0.f;
        if constexpr (HAS_BN) p1 = ep1[c];
#pragma unroll
        for (int r = 0; r < 4; ++r) {
            int row = rbase + r;
            if (row < nN) {
                float v;
                if constexpr (HAS_BN) v = acc[cf][r] * p0 + p1;
                else                  v = acc[cf][r] + p0;
                v = fmaxf(v, 0.f);
                out[(size_t)row * D + c] = __float2bfloat16(v);
            }
        }
    }
}

// ---------------- pooling
__global__ void zero_kernel(float* __restrict__ out, int n, int* __restrict__ cnt, int ncnt) {
    int i = blockIdx.x * 256 + threadIdx.x;
    if (i < n) out[i] = 0.f;
    if (i < ncnt) cnt[i] = 0;
}

// batch is sorted: run-length accumulate (bf16 in, f32 out), counts at flush
__global__ __launch_bounds__(256) void pool_kernel(const __hip_bfloat16* __restrict__ h,
                                                   const int* __restrict__ batch,
                                                   float* __restrict__ out,
                                                   int* __restrict__ cnt,
                                                   int nN, int span) {
    int grp = blockIdx.x * 16 + (threadIdx.x >> 4);
    int q = threadIdx.x & 15;
    int beg = grp * span;
    if (beg >= nN) return;
    int end = min(beg + span, nN);
    const uint4* h4 = reinterpret_cast<const uint4*>(h);
    int curg = batch[beg];
    float a[8] = {};
    int run = 0;
    for (int i = beg; i < end; ++i) {
        int g = batch[i];
        if (g != curg) {
            float* o = out + (size_t)curg * D + q * 8;
#pragma unroll
            for (int k = 0; k < 8; ++k) unsafeAtomicAdd(o + k, a[k]);
            if (q == 0) atomicAdd(&cnt[curg], run);
#pragma unroll
            for (int k = 0; k < 8; ++k) a[k] = 0.f;
            run = 0;
            curg = g;
        }
        uint4 v = h4[(size_t)i * 16 + q];
        a[0] += bflo(v.x); a[1] += bfhi(v.x); a[2] += bflo(v.y); a[3] += bfhi(v.y);
        a[4] += bflo(v.z); a[5] += bfhi(v.z); a[6] += bflo(v.w); a[7] += bfhi(v.w);
        ++run;
    }
    float* o = out + (size_t)curg * D + q * 8;
#pragma unroll
    for (int k = 0; k < 8; ++k) unsafeAtomicAdd(o + k, a[k]);
    if (q == 0) atomicAdd(&cnt[curg], run);
}

__global__ void div_kernel(float* __restrict__ out, const int* __restrict__ cnt, int n) {
    int i = blockIdx.x * 256 + threadIdx.x;
    if (i < n) out[i] /= fmaxf((float)cnt[i >> 7], 1.f);
}

extern "C" void kernel_launch(void* const* d_in, const int* in_sizes, int n_in,
                              void* d_out, int out_size, void* d_ws, size_t ws_size,
                              hipStream_t stream) {
    const float* x    = (const float*)d_in[0];
    const int*   ei   = (const int*)d_in[1];
    const int*   batch= (const int*)d_in[2];
    const float* w11 = (const float*)d_in[3];  const float* b11 = (const float*)d_in[4];
    const float* w12 = (const float*)d_in[5];  const float* b12 = (const float*)d_in[6];
    const float* w21 = (const float*)d_in[7];  const float* b21 = (const float*)d_in[8];
    const float* w22 = (const float*)d_in[9];  const float* b22 = (const float*)d_in[10];
    const float* w31 = (const float*)d_in[11]; const float* b31 = (const float*)d_in[12];
    const float* w32 = (const float*)d_in[13]; const float* b32 = (const float*)d_in[14];
    const float* bn1g = (const float*)d_in[15]; const float* bn1b = (const float*)d_in[16];
    const float* bn1m = (const float*)d_in[17]; const float* bn1v = (const float*)d_in[18];
    const float* bn2g = (const float*)d_in[19]; const float* bn2b = (const float*)d_in[20];
    const float* bn2m = (const float*)d_in[21]; const float* bn2v = (const float*)d_in[22];
    const float* bn3g = (const float*)d_in[23]; const float* bn3b = (const float*)d_in[24];
    const float* bn3m = (const float*)d_in[25]; const float* bn3v = (const float*)d_in[26];

    int nN = in_sizes[0] / D;
    int nE = in_sizes[1] / 2;
    int nG = out_size / D;

    const int* srcp = ei;
    const int* dstp = ei + nE;

    size_t NB2 = (size_t)nN * D * sizeof(__hip_bfloat16);   // bf16 feature buffer
    char* ws = (char*)d_ws;
    __hip_bfloat16* xb  = (__hip_bfloat16*)ws;
    __hip_bfloat16* S16 = (__hip_bfloat16*)(ws + NB2);
    __hip_bfloat16* M16 = (__hip_bfloat16*)(ws + 2 * NB2);
    __hip_bfloat16* P16 = (__hip_bfloat16*)(ws + 3 * NB2);
    __hip_bfloat16* Wp  = (__hip_bfloat16*)(ws + 4 * NB2);
    size_t wp_bytes = 6 * 2048 * 8 * sizeof(__hip_bfloat16);  // 196608
    float* aux = (float*)(ws + 4 * NB2 + wp_bytes);
    float* sc1 = aux + 0,   *sh1 = aux + 128;
    float* sc2 = aux + 256, *sh2 = aux + 384;
    float* sc3 = aux + 512, *sh3 = aux + 640;
    int*   cnt = (int*)(aux + 768);
    size_t aux_bytes = 4096;

    int nb = (nN + 255) / 256;
    size_t csr_bytes = ((size_t)(nN + 1) + (size_t)nN + (size_t)nE + (size_t)(nb + 1)) * sizeof(int);
    char* csr_base;
    bool per_layer_build;
    if (4 * NB2 + wp_bytes + aux_bytes + csr_bytes <= ws_size) {
        csr_base = ws + 4 * NB2 + wp_bytes + aux_bytes;   // persistent CSR
        per_layer_build = false;
    } else {
        csr_base = (char*)M16;     // overlay on M16 (dead during agg), rebuild per layer
        per_layer_build = true;
    }
    int* rowptr = (int*)csr_base;
    int* cursor = rowptr + (nN + 1);
    int* col    = cursor + nN;
    int* bsum   = col + nE;

    int eb = (nE + 255) / 256;
    auto build_csr = [&]() {
        zero_int_kernel<<<nb, 256, 0, stream>>>(cursor, nN);
        count_deg_kernel<<<eb, 256, 0, stream>>>(dstp, cursor, nE);
        scan1_kernel<<<nb, 256, 0, stream>>>(cursor, rowptr, bsum, nN);
        scan2_kernel<<<1, 64, 0, stream>>>(bsum, nb);
        scan3_kernel<<<nb, 256, 0, stream>>>(rowptr, cursor, bsum, nN, nb);
        fill_kernel<<<eb, 256, 0, stream>>>(srcp, dstp, cursor, col, nE);
    };

    bn_pre_kernel<<<1, 128, 0, stream>>>(bn1g, bn1b, bn1m, bn1v, b12, sc1, sh1);
    bn_pre_kernel<<<1, 128, 0, stream>>>(bn2g, bn2b, bn2m, bn2v, b22, sc2, sh2);
    bn_pre_kernel<<<1, 128, 0, stream>>>(bn3g, bn3b, bn3m, bn3v, b32, sc3, sh3);
    pack_w_kernel<<<48, 256, 0, stream>>>(w11, w12, w21, w22, w31, w32, Wp);

    long long n8 = (long long)nN * D / 8;
    cvt_kernel<<<(int)((n8 + 255) / 256), 256, 0, stream>>>(x, xb, n8);

    if (!per_layer_build) build_csr();

    int gemmBlocks = (nN + 63) / 64;
    int aggBlocks = (nN + 15) / 16;
    __hip_bfloat16* Wp1 = Wp + 0 * 16384; __hip_bfloat16* Wp2 = Wp + 1 * 16384;
    __hip_bfloat16* Wp3 = Wp + 2 * 16384; __hip_bfloat16* Wp4 = Wp + 3 * 16384;
    __hip_bfloat16* Wp5 = Wp + 4 * 16384; __hip_bfloat16* Wp6 = Wp + 5 * 16384;

    // ---- layer 1
    if (per_layer_build) build_csr();
    agg_kernel<<<aggBlocks, 256, 0, stream>>>(xb, S16, rowptr, col, nN);
    gemm_mfma_kernel<false><<<gemmBlocks, 256, 0, stream>>>(S16, Wp1, b11, nullptr, M16, nN);
    gemm_mfma_kernel<true><<<gemmBlocks, 256, 0, stream>>>(M16, Wp2, sc1, sh1, P16, nN);

    // ---- layer 2
    if (per_layer_build) build_csr();
    agg_kernel<<<aggBlocks, 256, 0, stream>>>(P16, S16, rowptr, col, nN);
    gemm_mfma_kernel<false><<<gemmBlocks, 256, 0, stream>>>(S16, Wp3, b21, nullptr, M16, nN);
    gemm_mfma_kernel<true><<<gemmBlocks, 256, 0, stream>>>(M16, Wp4, sc2, sh2, P16, nN);

    // ---- layer 3
    if (per_layer_build) build_csr();
    agg_kernel<<<aggBlocks, 256, 0, stream>>>(P16, S16, rowptr, col, nN);
    gemm_mfma_kernel<false><<<gemmBlocks, 256, 0, stream>>>(S16, Wp5, b31, nullptr, M16, nN);
    gemm_mfma_kernel<true><<<gemmBlocks, 256, 0, stream>>>(M16, Wp6, sc3, sh3, P16, nN);

    // ---- global mean pool (counts accumulated in pool_kernel)
    zero_kernel<<<(nG * D + 255) / 256, 256, 0, stream>>>((float*)d_out, nG * D, cnt, nG);
    int span = (nN + 4095) / 4096;
    int ngrp = (nN + span - 1) / span;
    pool_kernel<<<(ngrp + 15) / 16, 256, 0, stream>>>(P16, batch, (float*)d_out, cnt, nN, span);
    div_kernel<<<(nG * D + 255) / 256, 256, 0, stream>>>((float*)d_out, cnt, nG * D);
}

// Round 4
// 425.021 us; speedup vs baseline: 22.6243x; 1.5316x over previous
//
#include <hip/hip_runtime.h>
#include <hip/hip_bf16.h>
#include <cstdint>

static constexpr int D = 128;       // feature dim (D == H == O == 128)
static constexpr int SPANB = 9;     // bucket span = 512 nodes
static constexpr int CHUNK = 4096;  // edges per binning block

typedef __bf16 v8bf __attribute__((ext_vector_type(8)));
typedef float  v4f  __attribute__((ext_vector_type(4)));

__device__ inline float bflo(unsigned u) { return __uint_as_float(u << 16); }
__device__ inline float bfhi(unsigned u) { return __uint_as_float(u & 0xffff0000u); }
__device__ inline unsigned short bfbits(float f) {
    __hip_bfloat16 h = __float2bfloat16(f);
    return *reinterpret_cast<unsigned short*>(&h);
}
__device__ inline unsigned packbf(float a, float b) {
    return (unsigned)bfbits(a) | ((unsigned)bfbits(b) << 16);
}

// ---------------- BN precompute: scale = g*rsqrt(v+eps); shift = (lin_b - m)*scale + b
__global__ void bn_pre_kernel(const float* __restrict__ g, const float* __restrict__ b,
                              const float* __restrict__ m, const float* __restrict__ v,
                              const float* __restrict__ lin_b,
                              float* __restrict__ scale, float* __restrict__ shift) {
    int i = threadIdx.x;
    if (i < D) {
        float s = g[i] * rsqrtf(v[i] + 1e-5f);
        scale[i] = s;
        shift[i] = (lin_b[i] - m[i]) * s + b[i];
    }
}

// ---------------- f32 -> bf16 convert (8 elems / thread)
__global__ __launch_bounds__(256) void cvt_kernel(const float* __restrict__ in,
                                                  __hip_bfloat16* __restrict__ ob,
                                                  long long n8) {
    long long i = (long long)blockIdx.x * 256 + threadIdx.x;
    if (i >= n8) return;
    const float4* f4 = reinterpret_cast<const float4*>(in);
    float4 a = f4[i * 2], b = f4[i * 2 + 1];
    uint4 o = make_uint4(packbf(a.x, a.y), packbf(a.z, a.w),
                         packbf(b.x, b.y), packbf(b.z, b.w));
    reinterpret_cast<uint4*>(ob)[i] = o;
}

// ---------------- weight repack: Wp[w][ks][cf][lane][j] = bf16(W[ks*32+(l>>4)*8+j][cf*16+(l&15)])
__global__ __launch_bounds__(256) void pack_w_kernel(const float* w0, const float* w1,
                                                     const float* w2, const float* w3,
                                                     const float* w4, const float* w5,
                                                     __hip_bfloat16* __restrict__ Wp) {
    int idx = blockIdx.x * 256 + threadIdx.x;
    if (idx >= 6 * 2048) return;
    int widx = idx >> 11, r = idx & 2047;
    const float* W = widx == 0 ? w0 : widx == 1 ? w1 : widx == 2 ? w2
                   : widx == 3 ? w3 : widx == 4 ? w4 : w5;
    int l = r & 63, cf = (r >> 6) & 7, ks = r >> 9;
    int k0 = ks * 32 + (l >> 4) * 8, c = cf * 16 + (l & 15);
    unsigned o0 = packbf(W[(k0 + 0) * D + c], W[(k0 + 1) * D + c]);
    unsigned o1 = packbf(W[(k0 + 2) * D + c], W[(k0 + 3) * D + c]);
    unsigned o2 = packbf(W[(k0 + 4) * D + c], W[(k0 + 5) * D + c]);
    unsigned o3 = packbf(W[(k0 + 6) * D + c], W[(k0 + 7) * D + c]);
    reinterpret_cast<uint4*>(Wp + (size_t)idx * 8)[0] = make_uint4(o0, o1, o2, o3);
}

// ---------------- CSR build: bucketed counting sort ----------------
// buckets of 512 nodes; nbuk = ceil(nN/512) <= 256

// per-block histogram over buckets
__global__ __launch_bounds__(256) void hist_kernel(const int* __restrict__ dst,
                                                   int* __restrict__ blockhist,
                                                   int nE, int nbuk) {
    __shared__ int h[256];
    int t = threadIdx.x;
    h[t] = 0;
    __syncthreads();
    int base = blockIdx.x * CHUNK;
#pragma unroll
    for (int i = 0; i < CHUNK / 256; ++i) {
        int e = base + i * 256 + t;
        if (e < nE) atomicAdd(&h[dst[e] >> SPANB], 1);
    }
    __syncthreads();
    blockhist[blockIdx.x * 256 + t] = h[t];
}

// per-bucket scan over block counts; blockhist becomes per-(block,bucket) prefix
__global__ __launch_bounds__(256) void bscan_kernel(int* __restrict__ blockhist,
                                                    int* __restrict__ totals, int nblk) {
    __shared__ int s[256];
    int b = blockIdx.x, t = threadIdx.x;
    int running = 0;
    for (int base = 0; base < nblk; base += 256) {
        int idx = base + t;
        int v = (idx < nblk) ? blockhist[idx * 256 + b] : 0;
        s[t] = v;
        __syncthreads();
#pragma unroll
        for (int off = 1; off < 256; off <<= 1) {
            int add = (t >= off) ? s[t - off] : 0;
            __syncthreads();
            s[t] += add;
            __syncthreads();
        }
        if (idx < nblk) blockhist[idx * 256 + b] = running + s[t] - v;
        int tot = s[255];
        __syncthreads();
        running += tot;
    }
    if (t == 0) totals[b] = running;
}

// scan bucket totals -> bucketbase
__global__ void tscan_kernel(const int* __restrict__ totals,
                             int* __restrict__ bucketbase, int nbuk, int nE) {
    __shared__ int s[256];
    int t = threadIdx.x;
    int v = (t < nbuk) ? totals[t] : 0;
    s[t] = v;
    __syncthreads();
#pragma unroll
    for (int off = 1; off < 256; off <<= 1) {
        int add = (t >= off) ? s[t - off] : 0;
        __syncthreads();
        s[t] += add;
        __syncthreads();
    }
    if (t < nbuk) bucketbase[t] = s[t] - v;
    if (t == 0) bucketbase[nbuk] = nE;
}

// binning: write (src,dst) records to per-(block,bucket) exclusive ranges
__global__ __launch_bounds__(256) void fill2_kernel(const int* __restrict__ src,
                                                    const int* __restrict__ dst,
                                                    const int* __restrict__ blockhist,
                                                    const int* __restrict__ bucketbase,
                                                    uint2* __restrict__ records,
                                                    int nE, int nbuk) {
    __shared__ int cur[256];
    int t = threadIdx.x;
    if (t < nbuk) cur[t] = bucketbase[t] + blockhist[blockIdx.x * 256 + t];
    __syncthreads();
    int base = blockIdx.x * CHUNK;
#pragma unroll
    for (int i = 0; i < CHUNK / 256; ++i) {
        int e = base + i * 256 + t;
        if (e < nE) {
            int d = dst[e], s = src[e];
            int p = atomicAdd(&cur[d >> SPANB], 1);
            records[p] = make_uint2((unsigned)s, (unsigned)d);
        }
    }
}

// per-bucket fine CSR: local node histogram + scan + scatter into single-owner col region
__global__ __launch_bounds__(512) void csr2_kernel(const uint2* __restrict__ records,
                                                   const int* __restrict__ bucketbase,
                                                   int* __restrict__ rowptr,
                                                   int* __restrict__ col,
                                                   int nN, int nE) {
    __shared__ int cnt[512];
    __shared__ int cur[512];
    int b = blockIdx.x, t = threadIdx.x;
    int node0 = b << SPANB;
    cnt[t] = 0;
    __syncthreads();
    int rbeg = bucketbase[b], rend = bucketbase[b + 1];
    for (int r = rbeg + t; r < rend; r += 512)
        atomicAdd(&cnt[(int)records[r].y - node0], 1);
    __syncthreads();
    int v = cnt[t];
#pragma unroll
    for (int off = 1; off < 512; off <<= 1) {
        int add = (t >= off) ? cnt[t - off] : 0;
        __syncthreads();
        cnt[t] += add;
        __syncthreads();
    }
    int pos = rbeg + cnt[t] - v;    // exclusive prefix + bucket base
    if (node0 + t < nN) rowptr[node0 + t] = pos;
    if (b == 0 && t == 0) rowptr[nN] = nE;
    cur[t] = pos;
    __syncthreads();
    for (int r = rbeg + t; r < rend; r += 512) {
        uint2 rec = records[r];
        int p = atomicAdd(&cur[(int)rec.y - node0], 1);
        col[p] = (int)rec.x;
    }
}

// ---------------- gather aggregation (bf16): S[i] = h[i] + sum_{j in nbrs(i)} h[j]
// 16 lanes per node (16B each), 16 nodes per block; neighbor loop unrolled x4 for MLP
#define ACC8(vv) { a[0]+=bflo(vv.x); a[1]+=bfhi(vv.x); a[2]+=bflo(vv.y); a[3]+=bfhi(vv.y); \
                   a[4]+=bflo(vv.z); a[5]+=bfhi(vv.z); a[6]+=bflo(vv.w); a[7]+=bfhi(vv.w); }

__global__ __launch_bounds__(256) void agg_kernel(const __hip_bfloat16* __restrict__ h,
                                                  __hip_bfloat16* __restrict__ S,
                                                  const int* __restrict__ rowptr,
                                                  const int* __restrict__ col, int nN) {
    int node = blockIdx.x * 16 + (threadIdx.x >> 4);
    if (node >= nN) return;
    int q = threadIdx.x & 15;
    const uint4* h4 = reinterpret_cast<const uint4*>(h);
    uint4 u = h4[(size_t)node * 16 + q];
    float a[8];
    a[0] = bflo(u.x); a[1] = bfhi(u.x); a[2] = bflo(u.y); a[3] = bfhi(u.y);
    a[4] = bflo(u.z); a[5] = bfhi(u.z); a[6] = bflo(u.w); a[7] = bfhi(u.w);
    int beg = rowptr[node], end = rowptr[node + 1];
    int j = beg;
    for (; j + 3 < end; j += 4) {
        int s0 = col[j], s1 = col[j + 1], s2 = col[j + 2], s3 = col[j + 3];
        uint4 v0 = h4[(size_t)s0 * 16 + q];
        uint4 v1 = h4[(size_t)s1 * 16 + q];
        uint4 v2 = h4[(size_t)s2 * 16 + q];
        uint4 v3 = h4[(size_t)s3 * 16 + q];
        ACC8(v0); ACC8(v1); ACC8(v2); ACC8(v3);
    }
    for (; j < end; ++j) {
        uint4 v0 = h4[(size_t)col[j] * 16 + q];
        ACC8(v0);
    }
    uint4 o = make_uint4(packbf(a[0], a[1]), packbf(a[2], a[3]),
                         packbf(a[4], a[5]), packbf(a[6], a[7]));
    reinterpret_cast<uint4*>(S)[(size_t)node * 16 + q] = o;
}

// ---------------- MFMA GEMM (bf16 in/out, f32 accum) with fused epilogue
template<bool HAS_BN>
__global__ __launch_bounds__(256) void gemm_mfma_kernel(
    const __hip_bfloat16* __restrict__ A,
    const __hip_bfloat16* __restrict__ Wp,
    const float* __restrict__ ep0, const float* __restrict__ ep1,
    __hip_bfloat16* __restrict__ out, int nN) {
    int w = threadIdx.x >> 6;
    int l = threadIdx.x & 63;
    int row0 = blockIdx.x * 64 + w * 16;
    int ar = row0 + (l & 15);
    if (ar >= nN) ar = nN - 1;
    const v8bf* Arow = reinterpret_cast<const v8bf*>(A + (size_t)ar * D);
    const v8bf* Wv = reinterpret_cast<const v8bf*>(Wp);
    int kq = l >> 4;

    v4f acc[8] = {};
#pragma unroll
    for (int ks = 0; ks < 4; ++ks) {
        v8bf a = Arow[ks * 4 + kq];
#pragma unroll
        for (int cf = 0; cf < 8; ++cf) {
            v8bf b = Wv[(ks * 8 + cf) * 64 + l];
            acc[cf] = __builtin_amdgcn_mfma_f32_16x16x32_bf16(a, b, acc[cf], 0, 0, 0);
        }
    }

    int rbase = row0 + kq * 4;
#pragma unroll
    for (int cf = 0; cf < 8; ++cf) {
        int c = cf * 16 + (l & 15);
        float p0 = ep0[c];
        float p1 = 0.f;
        if constexpr (HAS_BN) p1 = ep1[c];
#pragma unroll
        for (int r = 0; r < 4; ++r) {
            int row = rbase + r;
            if (row < nN) {
                float vv;
                if constexpr (HAS_BN) vv = acc[cf][r] * p0 + p1;
                else                  vv = acc[cf][r] + p0;
                vv = fmaxf(vv, 0.f);
                out[(size_t)row * D + c] = __float2bfloat16(vv);
            }
        }
    }
}

// ---------------- pooling
__global__ void zero_kernel(float* __restrict__ out, int n, int* __restrict__ cnt, int ncnt) {
    int i = blockIdx.x * 256 + threadIdx.x;
    if (i < n) out[i] = 0.f;
    if (i < ncnt) cnt[i] = 0;
}

__global__ __launch_bounds__(256) void pool_kernel(const __hip_bfloat16* __restrict__ h,
                                                   const int* __restrict__ batch,
                                                   float* __restrict__ out,
                                                   int* __restrict__ cnt,
                                                   int nN, int span) {
    int grp = blockIdx.x * 16 + (threadIdx.x >> 4);
    int q = threadIdx.x & 15;
    int beg = grp * span;
    if (beg >= nN) return;
    int end = min(beg + span, nN);
    const uint4* h4 = reinterpret_cast<const uint4*>(h);
    int curg = batch[beg];
    float a[8] = {};
    int run = 0;
    for (int i = beg; i < end; ++i) {
        int g = batch[i];
        if (g != curg) {
            float* o = out + (size_t)curg * D + q * 8;
#pragma unroll
            for (int k = 0; k < 8; ++k) unsafeAtomicAdd(o + k, a[k]);
            if (q == 0) atomicAdd(&cnt[curg], run);
#pragma unroll
            for (int k = 0; k < 8; ++k) a[k] = 0.f;
            run = 0;
            curg = g;
        }
        uint4 v = h4[(size_t)i * 16 + q];
        ACC8(v);
        ++run;
    }
    float* o = out + (size_t)curg * D + q * 8;
#pragma unroll
    for (int k = 0; k < 8; ++k) unsafeAtomicAdd(o + k, a[k]);
    if (q == 0) atomicAdd(&cnt[curg], run);
}

__global__ void div_kernel(float* __restrict__ out, const int* __restrict__ cnt, int n) {
    int i = blockIdx.x * 256 + threadIdx.x;
    if (i < n) out[i] /= fmaxf((float)cnt[i >> 7], 1.f);
}

extern "C" void kernel_launch(void* const* d_in, const int* in_sizes, int n_in,
                              void* d_out, int out_size, void* d_ws, size_t ws_size,
                              hipStream_t stream) {
    const float* x    = (const float*)d_in[0];
    const int*   ei   = (const int*)d_in[1];
    const int*   batch= (const int*)d_in[2];
    const float* w11 = (const float*)d_in[3];  const float* b11 = (const float*)d_in[4];
    const float* w12 = (const float*)d_in[5];  const float* b12 = (const float*)d_in[6];
    const float* w21 = (const float*)d_in[7];  const float* b21 = (const float*)d_in[8];
    const float* w22 = (const float*)d_in[9];  const float* b22 = (const float*)d_in[10];
    const float* w31 = (const float*)d_in[11]; const float* b31 = (const float*)d_in[12];
    const float* w32 = (const float*)d_in[13]; const float* b32 = (const float*)d_in[14];
    const float* bn1g = (const float*)d_in[15]; const float* bn1b = (const float*)d_in[16];
    const float* bn1m = (const float*)d_in[17]; const float* bn1v = (const float*)d_in[18];
    const float* bn2g = (const float*)d_in[19]; const float* bn2b = (const float*)d_in[20];
    const float* bn2m = (const float*)d_in[21]; const float* bn2v = (const float*)d_in[22];
    const float* bn3g = (const float*)d_in[23]; const float* bn3b = (const float*)d_in[24];
    const float* bn3m = (const float*)d_in[25]; const float* bn3v = (const float*)d_in[26];

    int nN = in_sizes[0] / D;
    int nE = in_sizes[1] / 2;
    int nG = out_size / D;

    const int* srcp = ei;
    const int* dstp = ei + nE;

    size_t NB2 = (size_t)nN * D * sizeof(__hip_bfloat16);   // 25.6 MB
    char* ws = (char*)d_ws;
    __hip_bfloat16* S16 = (__hip_bfloat16*)ws;
    __hip_bfloat16* M16 = (__hip_bfloat16*)(ws + NB2);
    __hip_bfloat16* P16 = (__hip_bfloat16*)(ws + 2 * NB2);
    __hip_bfloat16* Wp  = (__hip_bfloat16*)(ws + 3 * NB2);
    size_t wp_bytes = 6 * 2048 * 8 * sizeof(__hip_bfloat16);  // 196608
    char* auxp = ws + 3 * NB2 + wp_bytes;
    size_t aux_bytes = 16384;
    float* sc1 = (float*)auxp + 0,   *sh1 = (float*)auxp + 128;
    float* sc2 = (float*)auxp + 256, *sh2 = (float*)auxp + 384;
    float* sc3 = (float*)auxp + 512, *sh3 = (float*)auxp + 640;
    int*   cnt = (int*)(auxp + 768 * 4);
    int*   bucketbase = (int*)(auxp + (768 + 64) * 4);   // nbuk+1 <= 257
    int*   totals     = bucketbase + 300;                // nbuk <= 256
    int* rowptr = (int*)(auxp + aux_bytes);
    int* col    = rowptr + (nN + 1);

    // CSR-build scratch overlays M16 (dead until layer-1 gemm1)
    uint2* records  = (uint2*)M16;                       // nE*8 <= NB2
    int* blockhist  = (int*)((char*)M16 + (size_t)nE * 8);

    int nbuk = (nN + 511) >> SPANB;                      // <= 256 for nN <= 131072
    int nblk = (nE + CHUNK - 1) / CHUNK;

    bn_pre_kernel<<<1, 128, 0, stream>>>(bn1g, bn1b, bn1m, bn1v, b12, sc1, sh1);
    bn_pre_kernel<<<1, 128, 0, stream>>>(bn2g, bn2b, bn2m, bn2v, b22, sc2, sh2);
    bn_pre_kernel<<<1, 128, 0, stream>>>(bn3g, bn3b, bn3m, bn3v, b32, sc3, sh3);
    pack_w_kernel<<<48, 256, 0, stream>>>(w11, w12, w21, w22, w31, w32, Wp);

    long long n8 = (long long)nN * D / 8;
    cvt_kernel<<<(int)((n8 + 255) / 256), 256, 0, stream>>>(x, (__hip_bfloat16*)P16, n8);

    // ---- CSR build (bucketed counting sort)
    hist_kernel<<<nblk, 256, 0, stream>>>(dstp, blockhist, nE, nbuk);
    bscan_kernel<<<nbuk, 256, 0, stream>>>(blockhist, totals, nblk);
    tscan_kernel<<<1, 256, 0, stream>>>(totals, bucketbase, nbuk, nE);
    fill2_kernel<<<nblk, 256, 0, stream>>>(srcp, dstp, blockhist, bucketbase, records, nE, nbuk);
    csr2_kernel<<<nbuk, 512, 0, stream>>>(records, bucketbase, rowptr, col, nN, nE);

    int gemmBlocks = (nN + 63) / 64;
    int aggBlocks = (nN + 15) / 16;
    __hip_bfloat16* Wp1 = Wp + 0 * 16384; __hip_bfloat16* Wp2 = Wp + 1 * 16384;
    __hip_bfloat16* Wp3 = Wp + 2 * 16384; __hip_bfloat16* Wp4 = Wp + 3 * 16384;
    __hip_bfloat16* Wp5 = Wp + 4 * 16384; __hip_bfloat16* Wp6 = Wp + 5 * 16384;

    // ---- layer 1 (x lives in P16 as bf16)
    agg_kernel<<<aggBlocks, 256, 0, stream>>>(P16, S16, rowptr, col, nN);
    gemm_mfma_kernel<false><<<gemmBlocks, 256, 0, stream>>>(S16, Wp1, b11, nullptr, M16, nN);
    gemm_mfma_kernel<true><<<gemmBlocks, 256, 0, stream>>>(M16, Wp2, sc1, sh1, P16, nN);

    // ---- layer 2
    agg_kernel<<<aggBlocks, 256, 0, stream>>>(P16, S16, rowptr, col, nN);
    gemm_mfma_kernel<false><<<gemmBlocks, 256, 0, stream>>>(S16, Wp3, b21, nullptr, M16, nN);
    gemm_mfma_kernel<true><<<gemmBlocks, 256, 0, stream>>>(M16, Wp4, sc2, sh2, P16, nN);

    // ---- layer 3
    agg_kernel<<<aggBlocks, 256, 0, stream>>>(P16, S16, rowptr, col, nN);
    gemm_mfma_kernel<false><<<gemmBlocks, 256, 0, stream>>>(S16, Wp5, b31, nullptr, M16, nN);
    gemm_mfma_kernel<true><<<gemmBlocks, 256, 0, stream>>>(M16, Wp6, sc3, sh3, P16, nN);

    // ---- global mean pool
    zero_kernel<<<(nG * D + 255) / 256, 256, 0, stream>>>((float*)d_out, nG * D, cnt, nG);
    int span = (nN + 4095) / 4096;
    int ngrp = (nN + span - 1) / span;
    pool_kernel<<<(ngrp + 15) / 16, 256, 0, stream>>>(P16, batch, (float*)d_out, cnt, nN, span);
    div_kernel<<<(nG * D + 255) / 256, 256, 0, stream>>>((float*)d_out, cnt, nG * D);
}

// Round 5
// 394.712 us; speedup vs baseline: 24.3615x; 1.0768x over previous
//
#include <hip/hip_runtime.h>
#include <hip/hip_bf16.h>
#include <cstdint>

static constexpr int D = 128;       // feature dim (D == H == O == 128)
static constexpr int SPANB = 9;     // bucket span = 512 nodes
static constexpr int CHUNK = 4096;  // edges per binning block

typedef __bf16 v8bf __attribute__((ext_vector_type(8)));
typedef float  v4f  __attribute__((ext_vector_type(4)));

__device__ inline float bflo(unsigned u) { return __uint_as_float(u << 16); }
__device__ inline float bfhi(unsigned u) { return __uint_as_float(u & 0xffff0000u); }
__device__ inline unsigned short bfbits(float f) {
    __hip_bfloat16 h = __float2bfloat16(f);
    return *reinterpret_cast<unsigned short*>(&h);
}
__device__ inline unsigned packbf(float a, float b) {
    return (unsigned)bfbits(a) | ((unsigned)bfbits(b) << 16);
}

// ---------------- BN precompute: scale = g*rsqrt(v+eps); shift = (lin_b - m)*scale + b
__global__ void bn_pre_kernel(const float* __restrict__ g, const float* __restrict__ b,
                              const float* __restrict__ m, const float* __restrict__ v,
                              const float* __restrict__ lin_b,
                              float* __restrict__ scale, float* __restrict__ shift) {
    int i = threadIdx.x;
    if (i < D) {
        float s = g[i] * rsqrtf(v[i] + 1e-5f);
        scale[i] = s;
        shift[i] = (lin_b[i] - m[i]) * s + b[i];
    }
}

// ---------------- f32 -> bf16 convert (8 elems / thread)
__global__ __launch_bounds__(256) void cvt_kernel(const float* __restrict__ in,
                                                  __hip_bfloat16* __restrict__ ob,
                                                  long long n8) {
    long long i = (long long)blockIdx.x * 256 + threadIdx.x;
    if (i >= n8) return;
    const float4* f4 = reinterpret_cast<const float4*>(in);
    float4 a = f4[i * 2], b = f4[i * 2 + 1];
    uint4 o = make_uint4(packbf(a.x, a.y), packbf(a.z, a.w),
                         packbf(b.x, b.y), packbf(b.z, b.w));
    reinterpret_cast<uint4*>(ob)[i] = o;
}

// ---------------- weight repack: Wp[w][ks][cf][lane][j] = bf16(W[ks*32+(l>>4)*8+j][cf*16+(l&15)])
// Used as the A-operand (= W^T fragment) in the swapped MFMA scheme.
__global__ __launch_bounds__(256) void pack_w_kernel(const float* w0, const float* w1,
                                                     const float* w2, const float* w3,
                                                     const float* w4, const float* w5,
                                                     __hip_bfloat16* __restrict__ Wp) {
    int idx = blockIdx.x * 256 + threadIdx.x;
    if (idx >= 6 * 2048) return;
    int widx = idx >> 11, r = idx & 2047;
    const float* W = widx == 0 ? w0 : widx == 1 ? w1 : widx == 2 ? w2
                   : widx == 3 ? w3 : widx == 4 ? w4 : w5;
    int l = r & 63, cf = (r >> 6) & 7, ks = r >> 9;
    int k0 = ks * 32 + (l >> 4) * 8, c = cf * 16 + (l & 15);
    unsigned o0 = packbf(W[(k0 + 0) * D + c], W[(k0 + 1) * D + c]);
    unsigned o1 = packbf(W[(k0 + 2) * D + c], W[(k0 + 3) * D + c]);
    unsigned o2 = packbf(W[(k0 + 4) * D + c], W[(k0 + 5) * D + c]);
    unsigned o3 = packbf(W[(k0 + 6) * D + c], W[(k0 + 7) * D + c]);
    reinterpret_cast<uint4*>(Wp + (size_t)idx * 8)[0] = make_uint4(o0, o1, o2, o3);
}

// ---------------- CSR build: bucketed counting sort ----------------
__global__ __launch_bounds__(256) void hist_kernel(const int* __restrict__ dst,
                                                   int* __restrict__ blockhist,
                                                   int nE, int nbuk) {
    __shared__ int h[256];
    int t = threadIdx.x;
    h[t] = 0;
    __syncthreads();
    int base = blockIdx.x * CHUNK;
#pragma unroll
    for (int i = 0; i < CHUNK / 256; ++i) {
        int e = base + i * 256 + t;
        if (e < nE) atomicAdd(&h[dst[e] >> SPANB], 1);
    }
    __syncthreads();
    blockhist[blockIdx.x * 256 + t] = h[t];
}

__global__ __launch_bounds__(256) void bscan_kernel(int* __restrict__ blockhist,
                                                    int* __restrict__ totals, int nblk) {
    __shared__ int s[256];
    int b = blockIdx.x, t = threadIdx.x;
    int running = 0;
    for (int base = 0; base < nblk; base += 256) {
        int idx = base + t;
        int v = (idx < nblk) ? blockhist[idx * 256 + b] : 0;
        s[t] = v;
        __syncthreads();
#pragma unroll
        for (int off = 1; off < 256; off <<= 1) {
            int add = (t >= off) ? s[t - off] : 0;
            __syncthreads();
            s[t] += add;
            __syncthreads();
        }
        if (idx < nblk) blockhist[idx * 256 + b] = running + s[t] - v;
        int tot = s[255];
        __syncthreads();
        running += tot;
    }
    if (t == 0) totals[b] = running;
}

__global__ void tscan_kernel(const int* __restrict__ totals,
                             int* __restrict__ bucketbase, int nbuk, int nE) {
    __shared__ int s[256];
    int t = threadIdx.x;
    int v = (t < nbuk) ? totals[t] : 0;
    s[t] = v;
    __syncthreads();
#pragma unroll
    for (int off = 1; off < 256; off <<= 1) {
        int add = (t >= off) ? s[t - off] : 0;
        __syncthreads();
        s[t] += add;
        __syncthreads();
    }
    if (t < nbuk) bucketbase[t] = s[t] - v;
    if (t == 0) bucketbase[nbuk] = nE;
}

// binning: packed record = (src << SPANB) | (dst & 511)  (src < 2^17, so 26 bits)
__global__ __launch_bounds__(256) void fill2_kernel(const int* __restrict__ src,
                                                    const int* __restrict__ dst,
                                                    const int* __restrict__ blockhist,
                                                    const int* __restrict__ bucketbase,
                                                    unsigned* __restrict__ records,
                                                    int nE, int nbuk) {
    __shared__ int cur[256];
    int t = threadIdx.x;
    if (t < nbuk) cur[t] = bucketbase[t] + blockhist[blockIdx.x * 256 + t];
    __syncthreads();
    int base = blockIdx.x * CHUNK;
#pragma unroll
    for (int i = 0; i < CHUNK / 256; ++i) {
        int e = base + i * 256 + t;
        if (e < nE) {
            int d = dst[e], s = src[e];
            int p = atomicAdd(&cur[d >> SPANB], 1);
            records[p] = ((unsigned)s << SPANB) | (unsigned)(d & ((1 << SPANB) - 1));
        }
    }
}

__global__ __launch_bounds__(512) void csr2_kernel(const unsigned* __restrict__ records,
                                                   const int* __restrict__ bucketbase,
                                                   int* __restrict__ rowptr,
                                                   int* __restrict__ col,
                                                   int nN, int nE) {
    __shared__ int cnt[512];
    __shared__ int cur[512];
    int b = blockIdx.x, t = threadIdx.x;
    int node0 = b << SPANB;
    cnt[t] = 0;
    __syncthreads();
    int rbeg = bucketbase[b], rend = bucketbase[b + 1];
    for (int r = rbeg + t; r < rend; r += 512)
        atomicAdd(&cnt[records[r] & ((1 << SPANB) - 1)], 1);
    __syncthreads();
    int v = cnt[t];
#pragma unroll
    for (int off = 1; off < 512; off <<= 1) {
        int add = (t >= off) ? cnt[t - off] : 0;
        __syncthreads();
        cnt[t] += add;
        __syncthreads();
    }
    int pos = rbeg + cnt[t] - v;
    if (node0 + t < nN) rowptr[node0 + t] = pos;
    if (b == 0 && t == 0) rowptr[nN] = nE;
    cur[t] = pos;
    __syncthreads();
    for (int r = rbeg + t; r < rend; r += 512) {
        unsigned rec = records[r];
        int p = atomicAdd(&cur[rec & ((1 << SPANB) - 1)], 1);
        col[p] = (int)(rec >> SPANB);
    }
}

// ---------------- gather aggregation (bf16): S[i] = h[i] + sum_{j in nbrs(i)} h[j]
#define ACC8(vv) { a[0]+=bflo(vv.x); a[1]+=bfhi(vv.x); a[2]+=bflo(vv.y); a[3]+=bfhi(vv.y); \
                   a[4]+=bflo(vv.z); a[5]+=bfhi(vv.z); a[6]+=bflo(vv.w); a[7]+=bfhi(vv.w); }

__global__ __launch_bounds__(256) void agg_kernel(const __hip_bfloat16* __restrict__ h,
                                                  __hip_bfloat16* __restrict__ S,
                                                  const int* __restrict__ rowptr,
                                                  const int* __restrict__ col, int nN) {
    int node = blockIdx.x * 16 + (threadIdx.x >> 4);
    if (node >= nN) return;
    int q = threadIdx.x & 15;
    const uint4* h4 = reinterpret_cast<const uint4*>(h);
    uint4 u = h4[(size_t)node * 16 + q];
    float a[8];
    a[0] = bflo(u.x); a[1] = bfhi(u.x); a[2] = bflo(u.y); a[3] = bfhi(u.y);
    a[4] = bflo(u.z); a[5] = bfhi(u.z); a[6] = bflo(u.w); a[7] = bfhi(u.w);
    int beg = rowptr[node], end = rowptr[node + 1];
    int j = beg;
    for (; j + 7 < end; j += 8) {
        int idx[8];
#pragma unroll
        for (int uu = 0; uu < 8; ++uu) idx[uu] = col[j + uu];
        uint4 v[8];
#pragma unroll
        for (int uu = 0; uu < 8; ++uu) v[uu] = h4[(size_t)idx[uu] * 16 + q];
#pragma unroll
        for (int uu = 0; uu < 8; ++uu) ACC8(v[uu]);
    }
    for (; j < end; ++j) {
        uint4 v0 = h4[(size_t)col[j] * 16 + q];
        ACC8(v0);
    }
    uint4 o = make_uint4(packbf(a[0], a[1]), packbf(a[2], a[3]),
                         packbf(a[4], a[5]), packbf(a[6], a[7]));
    reinterpret_cast<uint4*>(S)[(size_t)node * 16 + q] = o;
}

// ---------------- fused MLP: out = relu(BN(relu(S@W1 + b1) @ W2))  (bf16, f32 accum)
// Swapped MFMA: D = A.B with A = W^T frag (packed), B = feature-row frag.
// Lane owns node-row (l&15); per cf it holds 4 consecutive cols (q*4+{0..3}).
// Mid tile lives in per-wave LDS (16 rows x 128 cols bf16, XOR-swizzled).
__global__ __launch_bounds__(256) void mlp_fused_kernel(
    const __hip_bfloat16* __restrict__ A,
    const __hip_bfloat16* __restrict__ WpA,
    const __hip_bfloat16* __restrict__ WpB,
    const float* __restrict__ b1,
    const float* __restrict__ sc, const float* __restrict__ sh,
    __hip_bfloat16* __restrict__ out, int nN) {
    __shared__ __attribute__((aligned(16))) char smem[4][4096];
    int w = threadIdx.x >> 6, l = threadIdx.x & 63;
    int q = l >> 4, r16 = l & 15;
    int row0 = blockIdx.x * 64 + w * 16;
    int row = row0 + r16;
    int ar = row < nN ? row : nN - 1;
    const v8bf* Arow = reinterpret_cast<const v8bf*>(A + (size_t)ar * D);
    const v8bf* Wa = reinterpret_cast<const v8bf*>(WpA);
    const v8bf* Wb = reinterpret_cast<const v8bf*>(WpB);
    const float4* b14 = reinterpret_cast<const float4*>(b1);
    const float4* sc4 = reinterpret_cast<const float4*>(sc);
    const float4* sh4 = reinterpret_cast<const float4*>(sh);
    char* my = smem[w];
    int swz = (r16 & 7) << 4;

    // stage 1: mid = relu(S@W1 + b1)
    v4f acc[8] = {};
#pragma unroll
    for (int ks = 0; ks < 4; ++ks) {
        v8bf bfrag = Arow[ks * 4 + q];
#pragma unroll
        for (int cf = 0; cf < 8; ++cf)
            acc[cf] = __builtin_amdgcn_mfma_f32_16x16x32_bf16(
                Wa[(ks * 8 + cf) * 64 + l], bfrag, acc[cf], 0, 0, 0);
    }
#pragma unroll
    for (int cf = 0; cf < 8; ++cf) {
        float4 bb = b14[cf * 4 + q];
        float e0 = fmaxf(acc[cf][0] + bb.x, 0.f);
        float e1 = fmaxf(acc[cf][1] + bb.y, 0.f);
        float e2 = fmaxf(acc[cf][2] + bb.z, 0.f);
        float e3 = fmaxf(acc[cf][3] + bb.w, 0.f);
        int waddr = r16 * 256 + ((cf * 32 + q * 8) ^ swz);
        *reinterpret_cast<uint2*>(my + waddr) = make_uint2(packbf(e0, e1), packbf(e2, e3));
    }
    __syncthreads();

    // stage 2: out = relu(mid@W2 * sc + sh)
    v4f acc2[8] = {};
#pragma unroll
    for (int ks = 0; ks < 4; ++ks) {
        v8bf bfrag = *reinterpret_cast<v8bf*>(my + r16 * 256 + ((ks * 64 + q * 16) ^ swz));
#pragma unroll
        for (int cf = 0; cf < 8; ++cf)
            acc2[cf] = __builtin_amdgcn_mfma_f32_16x16x32_bf16(
                Wb[(ks * 8 + cf) * 64 + l], bfrag, acc2[cf], 0, 0, 0);
    }
    if (row < nN) {
#pragma unroll
        for (int cf = 0; cf < 8; ++cf) {
            float4 s0 = sc4[cf * 4 + q], s1 = sh4[cf * 4 + q];
            float e0 = fmaxf(acc2[cf][0] * s0.x + s1.x, 0.f);
            float e1 = fmaxf(acc2[cf][1] * s0.y + s1.y, 0.f);
            float e2 = fmaxf(acc2[cf][2] * s0.z + s1.z, 0.f);
            float e3 = fmaxf(acc2[cf][3] * s0.w + s1.w, 0.f);
            *reinterpret_cast<uint2*>(out + (size_t)row * D + cf * 16 + q * 4) =
                make_uint2(packbf(e0, e1), packbf(e2, e3));
        }
    }
}

// ---------------- pooling
__global__ void zero_kernel(float* __restrict__ out, int n, int* __restrict__ cnt, int ncnt) {
    int i = blockIdx.x * 256 + threadIdx.x;
    if (i < n) out[i] = 0.f;
    if (i < ncnt) cnt[i] = 0;
}

__global__ __launch_bounds__(256) void pool_kernel(const __hip_bfloat16* __restrict__ h,
                                                   const int* __restrict__ batch,
                                                   float* __restrict__ out,
                                                   int* __restrict__ cnt,
                                                   int nN, int span) {
    int grp = blockIdx.x * 16 + (threadIdx.x >> 4);
    int q = threadIdx.x & 15;
    int beg = grp * span;
    if (beg >= nN) return;
    int end = min(beg + span, nN);
    const uint4* h4 = reinterpret_cast<const uint4*>(h);
    int curg = batch[beg];
    float a[8] = {};
    int run = 0;
    for (int i = beg; i < end; ++i) {
        int g = batch[i];
        if (g != curg) {
            float* o = out + (size_t)curg * D + q * 8;
#pragma unroll
            for (int k = 0; k < 8; ++k) unsafeAtomicAdd(o + k, a[k]);
            if (q == 0) atomicAdd(&cnt[curg], run);
#pragma unroll
            for (int k = 0; k < 8; ++k) a[k] = 0.f;
            run = 0;
            curg = g;
        }
        uint4 v = h4[(size_t)i * 16 + q];
        ACC8(v);
        ++run;
    }
    float* o = out + (size_t)curg * D + q * 8;
#pragma unroll
    for (int k = 0; k < 8; ++k) unsafeAtomicAdd(o + k, a[k]);
    if (q == 0) atomicAdd(&cnt[curg], run);
}

__global__ void div_kernel(float* __restrict__ out, const int* __restrict__ cnt, int n) {
    int i = blockIdx.x * 256 + threadIdx.x;
    if (i < n) out[i] /= fmaxf((float)cnt[i >> 7], 1.f);
}

extern "C" void kernel_launch(void* const* d_in, const int* in_sizes, int n_in,
                              void* d_out, int out_size, void* d_ws, size_t ws_size,
                              hipStream_t stream) {
    const float* x    = (const float*)d_in[0];
    const int*   ei   = (const int*)d_in[1];
    const int*   batch= (const int*)d_in[2];
    const float* w11 = (const float*)d_in[3];  const float* b11 = (const float*)d_in[4];
    const float* w12 = (const float*)d_in[5];  const float* b12 = (const float*)d_in[6];
    const float* w21 = (const float*)d_in[7];  const float* b21 = (const float*)d_in[8];
    const float* w22 = (const float*)d_in[9];  const float* b22 = (const float*)d_in[10];
    const float* w31 = (const float*)d_in[11]; const float* b31 = (const float*)d_in[12];
    const float* w32 = (const float*)d_in[13]; const float* b32 = (const float*)d_in[14];
    const float* bn1g = (const float*)d_in[15]; const float* bn1b = (const float*)d_in[16];
    const float* bn1m = (const float*)d_in[17]; const float* bn1v = (const float*)d_in[18];
    const float* bn2g = (const float*)d_in[19]; const float* bn2b = (const float*)d_in[20];
    const float* bn2m = (const float*)d_in[21]; const float* bn2v = (const float*)d_in[22];
    const float* bn3g = (const float*)d_in[23]; const float* bn3b = (const float*)d_in[24];
    const float* bn3m = (const float*)d_in[25]; const float* bn3v = (const float*)d_in[26];

    int nN = in_sizes[0] / D;
    int nE = in_sizes[1] / 2;
    int nG = out_size / D;

    const int* srcp = ei;
    const int* dstp = ei + nE;

    size_t NB2 = (size_t)nN * D * sizeof(__hip_bfloat16);   // 25.6 MB
    char* ws = (char*)d_ws;
    __hip_bfloat16* S16 = (__hip_bfloat16*)ws;
    __hip_bfloat16* M16 = (__hip_bfloat16*)(ws + NB2);      // CSR-build scratch only
    __hip_bfloat16* P16 = (__hip_bfloat16*)(ws + 2 * NB2);
    __hip_bfloat16* Wp  = (__hip_bfloat16*)(ws + 3 * NB2);
    size_t wp_bytes = 6 * 2048 * 8 * sizeof(__hip_bfloat16);  // 196608
    char* auxp = ws + 3 * NB2 + wp_bytes;
    size_t aux_bytes = 16384;
    float* sc1 = (float*)auxp + 0,   *sh1 = (float*)auxp + 128;
    float* sc2 = (float*)auxp + 256, *sh2 = (float*)auxp + 384;
    float* sc3 = (float*)auxp + 512, *sh3 = (float*)auxp + 640;
    int*   cnt = (int*)(auxp + 768 * 4);
    int*   bucketbase = (int*)(auxp + (768 + 64) * 4);
    int*   totals     = bucketbase + 300;
    int* rowptr = (int*)(auxp + aux_bytes);
    int* col    = rowptr + (nN + 1);

    // CSR-build scratch overlays M16
    unsigned* records = (unsigned*)M16;                       // nE*4 bytes
    int* blockhist    = (int*)((char*)M16 + (size_t)nE * 4);

    int nbuk = (nN + 511) >> SPANB;
    int nblk = (nE + CHUNK - 1) / CHUNK;

    bn_pre_kernel<<<1, 128, 0, stream>>>(bn1g, bn1b, bn1m, bn1v, b12, sc1, sh1);
    bn_pre_kernel<<<1, 128, 0, stream>>>(bn2g, bn2b, bn2m, bn2v, b22, sc2, sh2);
    bn_pre_kernel<<<1, 128, 0, stream>>>(bn3g, bn3b, bn3m, bn3v, b32, sc3, sh3);
    pack_w_kernel<<<48, 256, 0, stream>>>(w11, w12, w21, w22, w31, w32, Wp);

    long long n8 = (long long)nN * D / 8;
    cvt_kernel<<<(int)((n8 + 255) / 256), 256, 0, stream>>>(x, (__hip_bfloat16*)P16, n8);

    // ---- CSR build (bucketed counting sort, packed records)
    hist_kernel<<<nblk, 256, 0, stream>>>(dstp, blockhist, nE, nbuk);
    bscan_kernel<<<nbuk, 256, 0, stream>>>(blockhist, totals, nblk);
    tscan_kernel<<<1, 256, 0, stream>>>(totals, bucketbase, nbuk, nE);
    fill2_kernel<<<nblk, 256, 0, stream>>>(srcp, dstp, blockhist, bucketbase, records, nE, nbuk);
    csr2_kernel<<<nbuk, 512, 0, stream>>>(records, bucketbase, rowptr, col, nN, nE);

    int mlpBlocks = (nN + 63) / 64;
    int aggBlocks = (nN + 15) / 16;
    __hip_bfloat16* Wp1 = Wp + 0 * 16384; __hip_bfloat16* Wp2 = Wp + 1 * 16384;
    __hip_bfloat16* Wp3 = Wp + 2 * 16384; __hip_bfloat16* Wp4 = Wp + 3 * 16384;
    __hip_bfloat16* Wp5 = Wp + 4 * 16384; __hip_bfloat16* Wp6 = Wp + 5 * 16384;

    // ---- layer 1 (x lives in P16 as bf16)
    agg_kernel<<<aggBlocks, 256, 0, stream>>>(P16, S16, rowptr, col, nN);
    mlp_fused_kernel<<<mlpBlocks, 256, 0, stream>>>(S16, Wp1, Wp2, b11, sc1, sh1, P16, nN);

    // ---- layer 2
    agg_kernel<<<aggBlocks, 256, 0, stream>>>(P16, S16, rowptr, col, nN);
    mlp_fused_kernel<<<mlpBlocks, 256, 0, stream>>>(S16, Wp3, Wp4, b21, sc2, sh2, P16, nN);

    // ---- layer 3
    agg_kernel<<<aggBlocks, 256, 0, stream>>>(P16, S16, rowptr, col, nN);
    mlp_fused_kernel<<<mlpBlocks, 256, 0, stream>>>(S16, Wp5, Wp6, b31, sc3, sh3, P16, nN);

    // ---- global mean pool
    zero_kernel<<<(nG * D + 255) / 256, 256, 0, stream>>>((float*)d_out, nG * D, cnt, nG);
    int span = (nN + 4095) / 4096;
    int ngrp = (nN + span - 1) / span;
    pool_kernel<<<(ngrp + 15) / 16, 256, 0, stream>>>(P16, batch, (float*)d_out, cnt, nN, span);
    div_kernel<<<(nG * D + 255) / 256, 256, 0, stream>>>((float*)d_out, cnt, nG * D);
}

// Round 6
// 346.569 us; speedup vs baseline: 27.7457x; 1.1389x over previous
//
#include <hip/hip_runtime.h>
#include <hip/hip_bf16.h>
#include <cstdint>

static constexpr int D = 128;       // feature dim (D == H == O == 128)
static constexpr int SPANB = 9;     // bucket span = 512 nodes
static constexpr int CHUNK = 4096;  // edges per binning block

typedef __bf16 v8bf __attribute__((ext_vector_type(8)));
typedef float  v4f  __attribute__((ext_vector_type(4)));

__device__ inline float bflo(unsigned u) { return __uint_as_float(u << 16); }
__device__ inline float bfhi(unsigned u) { return __uint_as_float(u & 0xffff0000u); }
__device__ inline unsigned short bfbits(float f) {
    __hip_bfloat16 h = __float2bfloat16(f);
    return *reinterpret_cast<unsigned short*>(&h);
}
__device__ inline unsigned packbf(float a, float b) {
    return (unsigned)bfbits(a) | ((unsigned)bfbits(b) << 16);
}

// ---------------- mega prep: pack_w (blocks 0-47) + bn_pre (48-50) + hist (51..50+nblk) + cvt (rest)
__global__ __launch_bounds__(256) void prep_kernel(
    const float* __restrict__ w11, const float* __restrict__ w12,
    const float* __restrict__ w21, const float* __restrict__ w22,
    const float* __restrict__ w31, const float* __restrict__ w32,
    __hip_bfloat16* __restrict__ Wp,
    const float* bn1g, const float* bn1b, const float* bn1m, const float* bn1v, const float* lb1,
    const float* bn2g, const float* bn2b, const float* bn2m, const float* bn2v, const float* lb2,
    const float* bn3g, const float* bn3b, const float* bn3m, const float* bn3v, const float* lb3,
    float* sc1, float* sh1, float* sc2, float* sh2, float* sc3, float* sh3,
    const float* __restrict__ x, __hip_bfloat16* __restrict__ xb, long long n8,
    const int* __restrict__ dst, int* __restrict__ blockhist, int nE, int nblk) {
    int b = blockIdx.x, t = threadIdx.x;
    if (b < 48) {
        // weight repack: Wp[w][ks][cf][lane][j] = bf16(W[ks*32+(l>>4)*8+j][cf*16+(l&15)])
        int idx = b * 256 + t;
        int widx = idx >> 11, r = idx & 2047;
        const float* W = widx == 0 ? w11 : widx == 1 ? w12 : widx == 2 ? w21
                       : widx == 3 ? w22 : widx == 4 ? w31 : w32;
        int l = r & 63, cf = (r >> 6) & 7, ks = r >> 9;
        int k0 = ks * 32 + (l >> 4) * 8, c = cf * 16 + (l & 15);
        unsigned o0 = packbf(W[(k0 + 0) * D + c], W[(k0 + 1) * D + c]);
        unsigned o1 = packbf(W[(k0 + 2) * D + c], W[(k0 + 3) * D + c]);
        unsigned o2 = packbf(W[(k0 + 4) * D + c], W[(k0 + 5) * D + c]);
        unsigned o3 = packbf(W[(k0 + 6) * D + c], W[(k0 + 7) * D + c]);
        reinterpret_cast<uint4*>(Wp + (size_t)idx * 8)[0] = make_uint4(o0, o1, o2, o3);
    } else if (b < 51) {
        if (t < D) {
            int j = b - 48;
            const float *g, *bb, *m, *v, *lb;
            float *sc, *sh;
            if (j == 0)      { g = bn1g; bb = bn1b; m = bn1m; v = bn1v; lb = lb1; sc = sc1; sh = sh1; }
            else if (j == 1) { g = bn2g; bb = bn2b; m = bn2m; v = bn2v; lb = lb2; sc = sc2; sh = sh2; }
            else             { g = bn3g; bb = bn3b; m = bn3m; v = bn3v; lb = lb3; sc = sc3; sh = sh3; }
            float s = g[t] * rsqrtf(v[t] + 1e-5f);
            sc[t] = s;
            sh[t] = (lb[t] - m[t]) * s + bb[t];
        }
    } else if (b < 51 + nblk) {
        __shared__ int h[256];
        h[t] = 0;
        __syncthreads();
        int base = (b - 51) * CHUNK;
#pragma unroll
        for (int i = 0; i < CHUNK / 256; ++i) {
            int e = base + i * 256 + t;
            if (e < nE) atomicAdd(&h[dst[e] >> SPANB], 1);
        }
        __syncthreads();
        blockhist[(b - 51) * 256 + t] = h[t];
    } else {
        long long i = (long long)(b - 51 - nblk) * 256 + t;
        if (i < n8) {
            const float4* f4 = reinterpret_cast<const float4*>(x);
            float4 a = f4[i * 2], bb = f4[i * 2 + 1];
            uint4 o = make_uint4(packbf(a.x, a.y), packbf(a.z, a.w),
                                 packbf(bb.x, bb.y), packbf(bb.z, bb.w));
            reinterpret_cast<uint4*>(xb)[i] = o;
        }
    }
}

// ---------------- CSR build rest ----------------
__global__ __launch_bounds__(256) void bscan_kernel(int* __restrict__ blockhist,
                                                    int* __restrict__ totals, int nblk) {
    __shared__ int s[256];
    int b = blockIdx.x, t = threadIdx.x;
    int running = 0;
    for (int base = 0; base < nblk; base += 256) {
        int idx = base + t;
        int v = (idx < nblk) ? blockhist[idx * 256 + b] : 0;
        s[t] = v;
        __syncthreads();
#pragma unroll
        for (int off = 1; off < 256; off <<= 1) {
            int add = (t >= off) ? s[t - off] : 0;
            __syncthreads();
            s[t] += add;
            __syncthreads();
        }
        if (idx < nblk) blockhist[idx * 256 + b] = running + s[t] - v;
        int tot = s[255];
        __syncthreads();
        running += tot;
    }
    if (t == 0) totals[b] = running;
}

__global__ void tscan_kernel(const int* __restrict__ totals,
                             int* __restrict__ bucketbase, int nbuk, int nE) {
    __shared__ int s[256];
    int t = threadIdx.x;
    int v = (t < nbuk) ? totals[t] : 0;
    s[t] = v;
    __syncthreads();
#pragma unroll
    for (int off = 1; off < 256; off <<= 1) {
        int add = (t >= off) ? s[t - off] : 0;
        __syncthreads();
        s[t] += add;
        __syncthreads();
    }
    if (t < nbuk) bucketbase[t] = s[t] - v;
    if (t == 0) bucketbase[nbuk] = nE;
}

// binning: packed record = (src << SPANB) | (dst & 511)
__global__ __launch_bounds__(256) void fill2_kernel(const int* __restrict__ src,
                                                    const int* __restrict__ dst,
                                                    const int* __restrict__ blockhist,
                                                    const int* __restrict__ bucketbase,
                                                    unsigned* __restrict__ records,
                                                    int nE, int nbuk) {
    __shared__ int cur[256];
    int t = threadIdx.x;
    if (t < nbuk) cur[t] = bucketbase[t] + blockhist[blockIdx.x * 256 + t];
    __syncthreads();
    int base = blockIdx.x * CHUNK;
#pragma unroll
    for (int i = 0; i < CHUNK / 256; ++i) {
        int e = base + i * 256 + t;
        if (e < nE) {
            int d = dst[e], s = src[e];
            int p = atomicAdd(&cur[d >> SPANB], 1);
            records[p] = ((unsigned)s << SPANB) | (unsigned)(d & ((1 << SPANB) - 1));
        }
    }
}

__global__ __launch_bounds__(512) void csr2_kernel(const unsigned* __restrict__ records,
                                                   const int* __restrict__ bucketbase,
                                                   int* __restrict__ rowptr,
                                                   int* __restrict__ col,
                                                   int nN, int nE) {
    __shared__ int cnt[512];
    __shared__ int cur[512];
    int b = blockIdx.x, t = threadIdx.x;
    int node0 = b << SPANB;
    cnt[t] = 0;
    __syncthreads();
    int rbeg = bucketbase[b], rend = bucketbase[b + 1];
    for (int r = rbeg + t; r < rend; r += 512)
        atomicAdd(&cnt[records[r] & ((1 << SPANB) - 1)], 1);
    __syncthreads();
    int v = cnt[t];
#pragma unroll
    for (int off = 1; off < 512; off <<= 1) {
        int add = (t >= off) ? cnt[t - off] : 0;
        __syncthreads();
        cnt[t] += add;
        __syncthreads();
    }
    int pos = rbeg + cnt[t] - v;
    if (node0 + t < nN) rowptr[node0 + t] = pos;
    if (b == 0 && t == 0) rowptr[nN] = nE;
    cur[t] = pos;
    __syncthreads();
    for (int r = rbeg + t; r < rend; r += 512) {
        unsigned rec = records[r];
        int p = atomicAdd(&cur[rec & ((1 << SPANB) - 1)], 1);
        col[p] = (int)(rec >> SPANB);
    }
}

// ---------------- gather aggregation (bf16): S[i] = h[i] + sum_{j in nbrs(i)} h[j]
#define ACC8(vv) { a[0]+=bflo(vv.x); a[1]+=bfhi(vv.x); a[2]+=bflo(vv.y); a[3]+=bfhi(vv.y); \
                   a[4]+=bflo(vv.z); a[5]+=bfhi(vv.z); a[6]+=bflo(vv.w); a[7]+=bfhi(vv.w); }

__global__ __launch_bounds__(256) void agg_kernel(const __hip_bfloat16* __restrict__ h,
                                                  __hip_bfloat16* __restrict__ S,
                                                  const int* __restrict__ rowptr,
                                                  const int* __restrict__ col, int nN) {
    int node = blockIdx.x * 16 + (threadIdx.x >> 4);
    if (node >= nN) return;
    int q = threadIdx.x & 15;
    const uint4* h4 = reinterpret_cast<const uint4*>(h);
    uint4 u = h4[(size_t)node * 16 + q];
    float a[8];
    a[0] = bflo(u.x); a[1] = bfhi(u.x); a[2] = bflo(u.y); a[3] = bfhi(u.y);
    a[4] = bflo(u.z); a[5] = bfhi(u.z); a[6] = bflo(u.w); a[7] = bfhi(u.w);
    int beg = rowptr[node], end = rowptr[node + 1];
    int j = beg;
    for (; j + 3 < end; j += 4) {
        int s0 = col[j], s1 = col[j + 1], s2 = col[j + 2], s3 = col[j + 3];
        uint4 v0 = h4[(size_t)s0 * 16 + q];
        uint4 v1 = h4[(size_t)s1 * 16 + q];
        uint4 v2 = h4[(size_t)s2 * 16 + q];
        uint4 v3 = h4[(size_t)s3 * 16 + q];
        ACC8(v0); ACC8(v1); ACC8(v2); ACC8(v3);
    }
    for (; j < end; ++j) {
        uint4 v0 = h4[(size_t)col[j] * 16 + q];
        ACC8(v0);
    }
    uint4 o = make_uint4(packbf(a[0], a[1]), packbf(a[2], a[3]),
                         packbf(a[4], a[5]), packbf(a[6], a[7]));
    reinterpret_cast<uint4*>(S)[(size_t)node * 16 + q] = o;
}

// ---------------- fused MLP: out = relu(BN(relu(S@W1 + b1) @ W2))  (bf16, f32 accum)
// Swapped MFMA: D = A.B with A = W^T frag (packed), B = feature-row frag.
// Each wave handles 32 rows (two 16-row halves sharing every W fragment load).
__global__ __launch_bounds__(256) void mlp_fused_kernel(
    const __hip_bfloat16* __restrict__ A,
    const __hip_bfloat16* __restrict__ WpA,
    const __hip_bfloat16* __restrict__ WpB,
    const float* __restrict__ b1,
    const float* __restrict__ sc, const float* __restrict__ sh,
    __hip_bfloat16* __restrict__ out, int nN) {
    __shared__ __attribute__((aligned(16))) char smem[4][8192];
    int w = threadIdx.x >> 6, l = threadIdx.x & 63;
    int q = l >> 4, r16 = l & 15;
    int row0 = blockIdx.x * 128 + w * 32;
    int rowA = row0 + r16, rowB = row0 + 16 + r16;
    int arA = rowA < nN ? rowA : nN - 1;
    int arB = rowB < nN ? rowB : nN - 1;
    const v8bf* ArA = reinterpret_cast<const v8bf*>(A + (size_t)arA * D);
    const v8bf* ArB = reinterpret_cast<const v8bf*>(A + (size_t)arB * D);
    const v8bf* Wa = reinterpret_cast<const v8bf*>(WpA);
    const v8bf* Wb = reinterpret_cast<const v8bf*>(WpB);
    const float4* b14 = reinterpret_cast<const float4*>(b1);
    const float4* sc4 = reinterpret_cast<const float4*>(sc);
    const float4* sh4 = reinterpret_cast<const float4*>(sh);
    char* my = smem[w];
    int swz = (r16 & 7) << 4;

    // stage 1: mid = relu(S@W1 + b1) for both 16-row halves
    v4f acc[2][8] = {};
#pragma unroll
    for (int ks = 0; ks < 4; ++ks) {
        v8bf bA = ArA[ks * 4 + q];
        v8bf bB = ArB[ks * 4 + q];
#pragma unroll
        for (int cf = 0; cf < 8; ++cf) {
            v8bf wa = Wa[(ks * 8 + cf) * 64 + l];
            acc[0][cf] = __builtin_amdgcn_mfma_f32_16x16x32_bf16(wa, bA, acc[0][cf], 0, 0, 0);
            acc[1][cf] = __builtin_amdgcn_mfma_f32_16x16x32_bf16(wa, bB, acc[1][cf], 0, 0, 0);
        }
    }
#pragma unroll
    for (int half = 0; half < 2; ++half) {
        char* base = my + half * 4096;
#pragma unroll
        for (int cf = 0; cf < 8; ++cf) {
            float4 bb = b14[cf * 4 + q];
            float e0 = fmaxf(acc[half][cf][0] + bb.x, 0.f);
            float e1 = fmaxf(acc[half][cf][1] + bb.y, 0.f);
            float e2 = fmaxf(acc[half][cf][2] + bb.z, 0.f);
            float e3 = fmaxf(acc[half][cf][3] + bb.w, 0.f);
            int waddr = r16 * 256 + ((cf * 32 + q * 8) ^ swz);
            *reinterpret_cast<uint2*>(base + waddr) = make_uint2(packbf(e0, e1), packbf(e2, e3));
        }
    }
    __syncthreads();

    // stage 2: out = relu(mid@W2 * sc + sh)
    v4f acc2[2][8] = {};
#pragma unroll
    for (int ks = 0; ks < 4; ++ks) {
        v8bf bA = *reinterpret_cast<v8bf*>(my + r16 * 256 + ((ks * 64 + q * 16) ^ swz));
        v8bf bB = *reinterpret_cast<v8bf*>(my + 4096 + r16 * 256 + ((ks * 64 + q * 16) ^ swz));
#pragma unroll
        for (int cf = 0; cf < 8; ++cf) {
            v8bf wb = Wb[(ks * 8 + cf) * 64 + l];
            acc2[0][cf] = __builtin_amdgcn_mfma_f32_16x16x32_bf16(wb, bA, acc2[0][cf], 0, 0, 0);
            acc2[1][cf] = __builtin_amdgcn_mfma_f32_16x16x32_bf16(wb, bB, acc2[1][cf], 0, 0, 0);
        }
    }
#pragma unroll
    for (int half = 0; half < 2; ++half) {
        int row = (half == 0) ? rowA : rowB;
        if (row < nN) {
#pragma unroll
            for (int cf = 0; cf < 8; ++cf) {
                float4 s0 = sc4[cf * 4 + q], s1 = sh4[cf * 4 + q];
                float e0 = fmaxf(acc2[half][cf][0] * s0.x + s1.x, 0.f);
                float e1 = fmaxf(acc2[half][cf][1] * s0.y + s1.y, 0.f);
                float e2 = fmaxf(acc2[half][cf][2] * s0.z + s1.z, 0.f);
                float e3 = fmaxf(acc2[half][cf][3] * s0.w + s1.w, 0.f);
                *reinterpret_cast<uint2*>(out + (size_t)row * D + cf * 16 + q * 4) =
                    make_uint2(packbf(e0, e1), packbf(e2, e3));
            }
        }
    }
}

// ---------------- pooling: one block per graph, binary-search boundaries, LDS reduce
__global__ __launch_bounds__(1024) void pool2_kernel(const __hip_bfloat16* __restrict__ h,
                                                     const int* __restrict__ batch,
                                                     float* __restrict__ out, int nN) {
    int g = blockIdx.x;
    int lo, hi;
    {
        int a = 0, b = nN;
        while (a < b) { int mid = (a + b) >> 1; if (batch[mid] < g) a = mid + 1; else b = mid; }
        lo = a;
        b = nN;
        while (a < b) { int mid = (a + b) >> 1; if (batch[mid] < g + 1) a = mid + 1; else b = mid; }
        hi = a;
    }
    int grp = threadIdx.x >> 4;   // 0..63
    int q = threadIdx.x & 15;
    float a[8] = {};
    const uint4* h4 = reinterpret_cast<const uint4*>(h);
    for (int i = lo + grp; i < hi; i += 64) {
        uint4 v = h4[(size_t)i * 16 + q];
        ACC8(v);
    }
    __shared__ float red[64][130];
#pragma unroll
    for (int k = 0; k < 8; ++k) red[grp][q * 8 + k] = a[k];
    __syncthreads();
    int t = threadIdx.x;
    if (t < D) {
        float s = 0.f;
#pragma unroll 8
        for (int r = 0; r < 64; ++r) s += red[r][t];
        out[(size_t)g * D + t] = s / fmaxf((float)(hi - lo), 1.f);
    }
}

extern "C" void kernel_launch(void* const* d_in, const int* in_sizes, int n_in,
                              void* d_out, int out_size, void* d_ws, size_t ws_size,
                              hipStream_t stream) {
    const float* x    = (const float*)d_in[0];
    const int*   ei   = (const int*)d_in[1];
    const int*   batch= (const int*)d_in[2];
    const float* w11 = (const float*)d_in[3];  const float* b11 = (const float*)d_in[4];
    const float* w12 = (const float*)d_in[5];  const float* b12 = (const float*)d_in[6];
    const float* w21 = (const float*)d_in[7];  const float* b21 = (const float*)d_in[8];
    const float* w22 = (const float*)d_in[9];  const float* b22 = (const float*)d_in[10];
    const float* w31 = (const float*)d_in[11]; const float* b31 = (const float*)d_in[12];
    const float* w32 = (const float*)d_in[13]; const float* b32 = (const float*)d_in[14];
    const float* bn1g = (const float*)d_in[15]; const float* bn1b = (const float*)d_in[16];
    const float* bn1m = (const float*)d_in[17]; const float* bn1v = (const float*)d_in[18];
    const float* bn2g = (const float*)d_in[19]; const float* bn2b = (const float*)d_in[20];
    const float* bn2m = (const float*)d_in[21]; const float* bn2v = (const float*)d_in[22];
    const float* bn3g = (const float*)d_in[23]; const float* bn3b = (const float*)d_in[24];
    const float* bn3m = (const float*)d_in[25]; const float* bn3v = (const float*)d_in[26];

    int nN = in_sizes[0] / D;
    int nE = in_sizes[1] / 2;
    int nG = out_size / D;

    const int* srcp = ei;
    const int* dstp = ei + nE;

    size_t NB2 = (size_t)nN * D * sizeof(__hip_bfloat16);   // 25.6 MB
    char* ws = (char*)d_ws;
    __hip_bfloat16* S16 = (__hip_bfloat16*)ws;
    __hip_bfloat16* M16 = (__hip_bfloat16*)(ws + NB2);      // CSR-build scratch only
    __hip_bfloat16* P16 = (__hip_bfloat16*)(ws + 2 * NB2);
    __hip_bfloat16* Wp  = (__hip_bfloat16*)(ws + 3 * NB2);
    size_t wp_bytes = 6 * 2048 * 8 * sizeof(__hip_bfloat16);  // 196608
    char* auxp = ws + 3 * NB2 + wp_bytes;
    size_t aux_bytes = 16384;
    float* sc1 = (float*)auxp + 0,   *sh1 = (float*)auxp + 128;
    float* sc2 = (float*)auxp + 256, *sh2 = (float*)auxp + 384;
    float* sc3 = (float*)auxp + 512, *sh3 = (float*)auxp + 640;
    int*   bucketbase = (int*)(auxp + (768 + 64) * 4);
    int*   totals     = bucketbase + 300;
    int* rowptr = (int*)(auxp + aux_bytes);
    int* col    = rowptr + (nN + 1);

    // CSR-build scratch overlays M16
    unsigned* records = (unsigned*)M16;                       // nE*4 bytes
    int* blockhist    = (int*)((char*)M16 + (size_t)nE * 4);

    int nbuk = (nN + 511) >> SPANB;
    int nblk = (nE + CHUNK - 1) / CHUNK;
    long long n8 = (long long)nN * D / 8;
    int cvtBlocks = (int)((n8 + 255) / 256);

    // ---- mega prep: pack + bn + hist + cvt
    prep_kernel<<<51 + nblk + cvtBlocks, 256, 0, stream>>>(
        w11, w12, w21, w22, w31, w32, Wp,
        bn1g, bn1b, bn1m, bn1v, b12,
        bn2g, bn2b, bn2m, bn2v, b22,
        bn3g, bn3b, bn3m, bn3v, b32,
        sc1, sh1, sc2, sh2, sc3, sh3,
        x, (__hip_bfloat16*)P16, n8,
        dstp, blockhist, nE, nblk);

    // ---- CSR build rest
    bscan_kernel<<<nbuk, 256, 0, stream>>>(blockhist, totals, nblk);
    tscan_kernel<<<1, 256, 0, stream>>>(totals, bucketbase, nbuk, nE);
    fill2_kernel<<<nblk, 256, 0, stream>>>(srcp, dstp, blockhist, bucketbase, records, nE, nbuk);
    csr2_kernel<<<nbuk, 512, 0, stream>>>(records, bucketbase, rowptr, col, nN, nE);

    int mlpBlocks = (nN + 127) / 128;
    int aggBlocks = (nN + 15) / 16;
    __hip_bfloat16* Wp1 = Wp + 0 * 16384; __hip_bfloat16* Wp2 = Wp + 1 * 16384;
    __hip_bfloat16* Wp3 = Wp + 2 * 16384; __hip_bfloat16* Wp4 = Wp + 3 * 16384;
    __hip_bfloat16* Wp5 = Wp + 4 * 16384; __hip_bfloat16* Wp6 = Wp + 5 * 16384;

    // ---- layer 1 (x lives in P16 as bf16)
    agg_kernel<<<aggBlocks, 256, 0, stream>>>(P16, S16, rowptr, col, nN);
    mlp_fused_kernel<<<mlpBlocks, 256, 0, stream>>>(S16, Wp1, Wp2, b11, sc1, sh1, P16, nN);

    // ---- layer 2
    agg_kernel<<<aggBlocks, 256, 0, stream>>>(P16, S16, rowptr, col, nN);
    mlp_fused_kernel<<<mlpBlocks, 256, 0, stream>>>(S16, Wp3, Wp4, b21, sc2, sh2, P16, nN);

    // ---- layer 3
    agg_kernel<<<aggBlocks, 256, 0, stream>>>(P16, S16, rowptr, col, nN);
    mlp_fused_kernel<<<mlpBlocks, 256, 0, stream>>>(S16, Wp5, Wp6, b31, sc3, sh3, P16, nN);

    // ---- global mean pool: one block per graph
    pool2_kernel<<<nG, 1024, 0, stream>>>(P16, batch, (float*)d_out, nN);
}

// Round 7
// 330.278 us; speedup vs baseline: 29.1143x; 1.0493x over previous
//
#include <hip/hip_runtime.h>
#include <hip/hip_bf16.h>
#include <cstdint>

static constexpr int D = 128;       // feature dim (D == H == O == 128)
static constexpr int SPANB = 9;     // bucket span = 512 nodes
static constexpr int CHUNK = 4096;  // edges per binning block

typedef __bf16 v8bf __attribute__((ext_vector_type(8)));
typedef float  v4f  __attribute__((ext_vector_type(4)));

__device__ inline float bflo(unsigned u) { return __uint_as_float(u << 16); }
__device__ inline float bfhi(unsigned u) { return __uint_as_float(u & 0xffff0000u); }
__device__ inline unsigned short bfbits(float f) {
    __hip_bfloat16 h = __float2bfloat16(f);
    return *reinterpret_cast<unsigned short*>(&h);
}
__device__ inline unsigned packbf(float a, float b) {
    return (unsigned)bfbits(a) | ((unsigned)bfbits(b) << 16);
}

// ---------------- mega prep: pack_w (blocks 0-47) + bn_pre (48-50) + hist (51..50+nblk) + cvt (rest)
__global__ __launch_bounds__(256) void prep_kernel(
    const float* __restrict__ w11, const float* __restrict__ w12,
    const float* __restrict__ w21, const float* __restrict__ w22,
    const float* __restrict__ w31, const float* __restrict__ w32,
    __hip_bfloat16* __restrict__ Wp,
    const float* bn1g, const float* bn1b, const float* bn1m, const float* bn1v, const float* lb1,
    const float* bn2g, const float* bn2b, const float* bn2m, const float* bn2v, const float* lb2,
    const float* bn3g, const float* bn3b, const float* bn3m, const float* bn3v, const float* lb3,
    float* sc1, float* sh1, float* sc2, float* sh2, float* sc3, float* sh3,
    const float* __restrict__ x, __hip_bfloat16* __restrict__ xb, long long n8,
    const int* __restrict__ dst, int* __restrict__ blockhist, int nE, int nblk) {
    int b = blockIdx.x, t = threadIdx.x;
    if (b < 48) {
        // weight repack: Wp[w][ks][cf][lane][j] = bf16(W[ks*32+(l>>4)*8+j][cf*16+(l&15)])
        int idx = b * 256 + t;
        int widx = idx >> 11, r = idx & 2047;
        const float* W = widx == 0 ? w11 : widx == 1 ? w12 : widx == 2 ? w21
                       : widx == 3 ? w22 : widx == 4 ? w31 : w32;
        int l = r & 63, cf = (r >> 6) & 7, ks = r >> 9;
        int k0 = ks * 32 + (l >> 4) * 8, c = cf * 16 + (l & 15);
        unsigned o0 = packbf(W[(k0 + 0) * D + c], W[(k0 + 1) * D + c]);
        unsigned o1 = packbf(W[(k0 + 2) * D + c], W[(k0 + 3) * D + c]);
        unsigned o2 = packbf(W[(k0 + 4) * D + c], W[(k0 + 5) * D + c]);
        unsigned o3 = packbf(W[(k0 + 6) * D + c], W[(k0 + 7) * D + c]);
        reinterpret_cast<uint4*>(Wp + (size_t)idx * 8)[0] = make_uint4(o0, o1, o2, o3);
    } else if (b < 51) {
        if (t < D) {
            int j = b - 48;
            const float *g, *bb, *m, *v, *lb;
            float *sc, *sh;
            if (j == 0)      { g = bn1g; bb = bn1b; m = bn1m; v = bn1v; lb = lb1; sc = sc1; sh = sh1; }
            else if (j == 1) { g = bn2g; bb = bn2b; m = bn2m; v = bn2v; lb = lb2; sc = sc2; sh = sh2; }
            else             { g = bn3g; bb = bn3b; m = bn3m; v = bn3v; lb = lb3; sc = sc3; sh = sh3; }
            float s = g[t] * rsqrtf(v[t] + 1e-5f);
            sc[t] = s;
            sh[t] = (lb[t] - m[t]) * s + bb[t];
        }
    } else if (b < 51 + nblk) {
        __shared__ int h[256];
        h[t] = 0;
        __syncthreads();
        int base = (b - 51) * CHUNK;
#pragma unroll
        for (int i = 0; i < CHUNK / 256; ++i) {
            int e = base + i * 256 + t;
            if (e < nE) atomicAdd(&h[dst[e] >> SPANB], 1);
        }
        __syncthreads();
        blockhist[(b - 51) * 256 + t] = h[t];
    } else {
        long long i = (long long)(b - 51 - nblk) * 256 + t;
        if (i < n8) {
            const float4* f4 = reinterpret_cast<const float4*>(x);
            float4 a = f4[i * 2], bb = f4[i * 2 + 1];
            uint4 o = make_uint4(packbf(a.x, a.y), packbf(a.z, a.w),
                                 packbf(bb.x, bb.y), packbf(bb.z, bb.w));
            reinterpret_cast<uint4*>(xb)[i] = o;
        }
    }
}

// ---------------- CSR build rest ----------------
__global__ __launch_bounds__(256) void bscan_kernel(int* __restrict__ blockhist,
                                                    int* __restrict__ totals, int nblk) {
    __shared__ int s[256];
    int b = blockIdx.x, t = threadIdx.x;
    int running = 0;
    for (int base = 0; base < nblk; base += 256) {
        int idx = base + t;
        int v = (idx < nblk) ? blockhist[idx * 256 + b] : 0;
        s[t] = v;
        __syncthreads();
#pragma unroll
        for (int off = 1; off < 256; off <<= 1) {
            int add = (t >= off) ? s[t - off] : 0;
            __syncthreads();
            s[t] += add;
            __syncthreads();
        }
        if (idx < nblk) blockhist[idx * 256 + b] = running + s[t] - v;
        int tot = s[255];
        __syncthreads();
        running += tot;
    }
    if (t == 0) totals[b] = running;
}

__global__ void tscan_kernel(const int* __restrict__ totals,
                             int* __restrict__ bucketbase, int nbuk, int nE) {
    __shared__ int s[256];
    int t = threadIdx.x;
    int v = (t < nbuk) ? totals[t] : 0;
    s[t] = v;
    __syncthreads();
#pragma unroll
    for (int off = 1; off < 256; off <<= 1) {
        int add = (t >= off) ? s[t - off] : 0;
        __syncthreads();
        s[t] += add;
        __syncthreads();
    }
    if (t < nbuk) bucketbase[t] = s[t] - v;
    if (t == 0) bucketbase[nbuk] = nE;
}

// binning: packed record = (src << SPANB) | (dst & 511)
__global__ __launch_bounds__(256) void fill2_kernel(const int* __restrict__ src,
                                                    const int* __restrict__ dst,
                                                    const int* __restrict__ blockhist,
                                                    const int* __restrict__ bucketbase,
                                                    unsigned* __restrict__ records,
                                                    int nE, int nbuk) {
    __shared__ int cur[256];
    int t = threadIdx.x;
    if (t < nbuk) cur[t] = bucketbase[t] + blockhist[blockIdx.x * 256 + t];
    __syncthreads();
    int base = blockIdx.x * CHUNK;
#pragma unroll
    for (int i = 0; i < CHUNK / 256; ++i) {
        int e = base + i * 256 + t;
        if (e < nE) {
            int d = dst[e], s = src[e];
            int p = atomicAdd(&cur[d >> SPANB], 1);
            records[p] = ((unsigned)s << SPANB) | (unsigned)(d & ((1 << SPANB) - 1));
        }
    }
}

__global__ __launch_bounds__(512) void csr2_kernel(const unsigned* __restrict__ records,
                                                   const int* __restrict__ bucketbase,
                                                   int* __restrict__ rowptr,
                                                   int* __restrict__ col,
                                                   int nN, int nE) {
    __shared__ int cnt[512];
    __shared__ int cur[512];
    int b = blockIdx.x, t = threadIdx.x;
    int node0 = b << SPANB;
    cnt[t] = 0;
    __syncthreads();
    int rbeg = bucketbase[b], rend = bucketbase[b + 1];
    for (int r = rbeg + t; r < rend; r += 512)
        atomicAdd(&cnt[records[r] & ((1 << SPANB) - 1)], 1);
    __syncthreads();
    int v = cnt[t];
#pragma unroll
    for (int off = 1; off < 512; off <<= 1) {
        int add = (t >= off) ? cnt[t - off] : 0;
        __syncthreads();
        cnt[t] += add;
        __syncthreads();
    }
    int pos = rbeg + cnt[t] - v;
    if (node0 + t < nN) rowptr[node0 + t] = pos;
    if (b == 0 && t == 0) rowptr[nN] = nE;
    cur[t] = pos;
    __syncthreads();
    for (int r = rbeg + t; r < rend; r += 512) {
        unsigned rec = records[r];
        int p = atomicAdd(&cur[rec & ((1 << SPANB) - 1)], 1);
        col[p] = (int)(rec >> SPANB);
    }
}

#define ACC8(vv) { a[0]+=bflo(vv.x); a[1]+=bfhi(vv.x); a[2]+=bflo(vv.y); a[3]+=bfhi(vv.y); \
                   a[4]+=bflo(vv.z); a[5]+=bfhi(vv.z); a[6]+=bflo(vv.w); a[7]+=bfhi(vv.w); }

// ---------------- fused layer: Hout = relu(BN(relu((Hin + gather(Hin))@W1 + b1)@W2))
// Block = 256 thr, 64 rows. Phase 1: gather-aggregate into LDS (swizzled rows).
// Phase 2: per-wave 16-row swapped-MFMA 2-stage MLP; mid tile aliases the wave's
// own 16 Sl rows (only this wave reads them).
__global__ __launch_bounds__(256) void layer_kernel(
    const __hip_bfloat16* __restrict__ Hin,
    const int* __restrict__ rowptr, const int* __restrict__ col,
    const __hip_bfloat16* __restrict__ WpA, const __hip_bfloat16* __restrict__ WpB,
    const float* __restrict__ b1,
    const float* __restrict__ sc, const float* __restrict__ sh,
    __hip_bfloat16* __restrict__ Hout, int nN) {
    __shared__ __attribute__((aligned(16))) char Sl[64 * 256];   // 16 KB
    int t = threadIdx.x;
    int row0 = blockIdx.x * 64;

    // ---- phase 1: gather
    {
        int grp = t >> 4, q = t & 15;
        const uint4* h4 = reinterpret_cast<const uint4*>(Hin);
#pragma unroll
        for (int n = 0; n < 4; ++n) {
            int r = grp * 4 + n;
            int node = row0 + r;
            int waddr = r * 256 + ((q * 16) ^ ((r & 7) << 4));
            if (node >= nN) {
                *reinterpret_cast<uint4*>(Sl + waddr) = make_uint4(0, 0, 0, 0);
                continue;
            }
            uint4 u = h4[(size_t)node * 16 + q];
            float a[8];
            a[0] = bflo(u.x); a[1] = bfhi(u.x); a[2] = bflo(u.y); a[3] = bfhi(u.y);
            a[4] = bflo(u.z); a[5] = bfhi(u.z); a[6] = bflo(u.w); a[7] = bfhi(u.w);
            int beg = rowptr[node], end = rowptr[node + 1];
            int j = beg;
            for (; j + 3 < end; j += 4) {
                int s0 = col[j], s1 = col[j + 1], s2 = col[j + 2], s3 = col[j + 3];
                uint4 v0 = h4[(size_t)s0 * 16 + q];
                uint4 v1 = h4[(size_t)s1 * 16 + q];
                uint4 v2 = h4[(size_t)s2 * 16 + q];
                uint4 v3 = h4[(size_t)s3 * 16 + q];
                ACC8(v0); ACC8(v1); ACC8(v2); ACC8(v3);
            }
            for (; j < end; ++j) {
                uint4 v0 = h4[(size_t)col[j] * 16 + q];
                ACC8(v0);
            }
            *reinterpret_cast<uint4*>(Sl + waddr) =
                make_uint4(packbf(a[0], a[1]), packbf(a[2], a[3]),
                           packbf(a[4], a[5]), packbf(a[6], a[7]));
        }
    }
    __syncthreads();

    // ---- phase 2: MLP
    int w = t >> 6, l = t & 63;
    int q2 = l >> 4, r16 = l & 15;
    int lrow = w * 16 + r16;
    int row = row0 + lrow;
    int swz = (r16 & 7) << 4;            // lrow&7 == r16&7
    char* srow = Sl + lrow * 256;
    char* mid = Sl + w * 4096;           // aliases this wave's own 16 rows
    const v8bf* Wa = reinterpret_cast<const v8bf*>(WpA);
    const v8bf* Wb = reinterpret_cast<const v8bf*>(WpB);
    const float4* b14 = reinterpret_cast<const float4*>(b1);
    const float4* sc4 = reinterpret_cast<const float4*>(sc);
    const float4* sh4 = reinterpret_cast<const float4*>(sh);

    // stage 1
    v4f acc[8] = {};
#pragma unroll
    for (int ks = 0; ks < 4; ++ks) {
        v8bf bfrag = *reinterpret_cast<v8bf*>(srow + (((ks * 4 + q2) * 16) ^ swz));
#pragma unroll
        for (int cf = 0; cf < 8; ++cf)
            acc[cf] = __builtin_amdgcn_mfma_f32_16x16x32_bf16(
                Wa[(ks * 8 + cf) * 64 + l], bfrag, acc[cf], 0, 0, 0);
    }
    __syncthreads();   // all Sl reads done before mid overwrites

    // mid = relu(acc + b1)
#pragma unroll
    for (int cf = 0; cf < 8; ++cf) {
        float4 bb = b14[cf * 4 + q2];
        float e0 = fmaxf(acc[cf][0] + bb.x, 0.f);
        float e1 = fmaxf(acc[cf][1] + bb.y, 0.f);
        float e2 = fmaxf(acc[cf][2] + bb.z, 0.f);
        float e3 = fmaxf(acc[cf][3] + bb.w, 0.f);
        int waddr = r16 * 256 + ((cf * 32 + q2 * 8) ^ swz);
        *reinterpret_cast<uint2*>(mid + waddr) = make_uint2(packbf(e0, e1), packbf(e2, e3));
    }
    __syncthreads();

    // stage 2
    v4f acc2[8] = {};
#pragma unroll
    for (int ks = 0; ks < 4; ++ks) {
        v8bf bfrag = *reinterpret_cast<v8bf*>(mid + r16 * 256 + ((ks * 64 + q2 * 16) ^ swz));
#pragma unroll
        for (int cf = 0; cf < 8; ++cf)
            acc2[cf] = __builtin_amdgcn_mfma_f32_16x16x32_bf16(
                Wb[(ks * 8 + cf) * 64 + l], bfrag, acc2[cf], 0, 0, 0);
    }
    if (row < nN) {
#pragma unroll
        for (int cf = 0; cf < 8; ++cf) {
            float4 s0 = sc4[cf * 4 + q2], s1 = sh4[cf * 4 + q2];
            float e0 = fmaxf(acc2[cf][0] * s0.x + s1.x, 0.f);
            float e1 = fmaxf(acc2[cf][1] * s0.y + s1.y, 0.f);
            float e2 = fmaxf(acc2[cf][2] * s0.z + s1.z, 0.f);
            float e3 = fmaxf(acc2[cf][3] * s0.w + s1.w, 0.f);
            *reinterpret_cast<uint2*>(Hout + (size_t)row * D + cf * 16 + q2 * 4) =
                make_uint2(packbf(e0, e1), packbf(e2, e3));
        }
    }
}

// ---------------- pooling: one block per graph, binary-search boundaries, LDS reduce
__global__ __launch_bounds__(1024) void pool2_kernel(const __hip_bfloat16* __restrict__ h,
                                                     const int* __restrict__ batch,
                                                     float* __restrict__ out, int nN) {
    int g = blockIdx.x;
    int lo, hi;
    {
        int a = 0, b = nN;
        while (a < b) { int mid = (a + b) >> 1; if (batch[mid] < g) a = mid + 1; else b = mid; }
        lo = a;
        b = nN;
        while (a < b) { int mid = (a + b) >> 1; if (batch[mid] < g + 1) a = mid + 1; else b = mid; }
        hi = a;
    }
    int grp = threadIdx.x >> 4;   // 0..63
    int q = threadIdx.x & 15;
    float a[8] = {};
    const uint4* h4 = reinterpret_cast<const uint4*>(h);
    for (int i = lo + grp; i < hi; i += 64) {
        uint4 v = h4[(size_t)i * 16 + q];
        ACC8(v);
    }
    __shared__ float red[64][130];
#pragma unroll
    for (int k = 0; k < 8; ++k) red[grp][q * 8 + k] = a[k];
    __syncthreads();
    int t = threadIdx.x;
    if (t < D) {
        float s = 0.f;
#pragma unroll 8
        for (int r = 0; r < 64; ++r) s += red[r][t];
        out[(size_t)g * D + t] = s / fmaxf((float)(hi - lo), 1.f);
    }
}

extern "C" void kernel_launch(void* const* d_in, const int* in_sizes, int n_in,
                              void* d_out, int out_size, void* d_ws, size_t ws_size,
                              hipStream_t stream) {
    const float* x    = (const float*)d_in[0];
    const int*   ei   = (const int*)d_in[1];
    const int*   batch= (const int*)d_in[2];
    const float* w11 = (const float*)d_in[3];  const float* b11 = (const float*)d_in[4];
    const float* w12 = (const float*)d_in[5];  const float* b12 = (const float*)d_in[6];
    const float* w21 = (const float*)d_in[7];  const float* b21 = (const float*)d_in[8];
    const float* w22 = (const float*)d_in[9];  const float* b22 = (const float*)d_in[10];
    const float* w31 = (const float*)d_in[11]; const float* b31 = (const float*)d_in[12];
    const float* w32 = (const float*)d_in[13]; const float* b32 = (const float*)d_in[14];
    const float* bn1g = (const float*)d_in[15]; const float* bn1b = (const float*)d_in[16];
    const float* bn1m = (const float*)d_in[17]; const float* bn1v = (const float*)d_in[18];
    const float* bn2g = (const float*)d_in[19]; const float* bn2b = (const float*)d_in[20];
    const float* bn2m = (const float*)d_in[21]; const float* bn2v = (const float*)d_in[22];
    const float* bn3g = (const float*)d_in[23]; const float* bn3b = (const float*)d_in[24];
    const float* bn3m = (const float*)d_in[25]; const float* bn3v = (const float*)d_in[26];

    int nN = in_sizes[0] / D;
    int nE = in_sizes[1] / 2;
    int nG = out_size / D;

    const int* srcp = ei;
    const int* dstp = ei + nE;

    size_t NB2 = (size_t)nN * D * sizeof(__hip_bfloat16);   // 25.6 MB
    char* ws = (char*)d_ws;
    __hip_bfloat16* A16 = (__hip_bfloat16*)ws;              // feature ping
    __hip_bfloat16* B16 = (__hip_bfloat16*)(ws + NB2);      // feature pong (+ CSR scratch early)
    __hip_bfloat16* Wp  = (__hip_bfloat16*)(ws + 2 * NB2);
    size_t wp_bytes = 6 * 2048 * 8 * sizeof(__hip_bfloat16);  // 196608
    char* auxp = ws + 2 * NB2 + wp_bytes;
    size_t aux_bytes = 16384;
    float* sc1 = (float*)auxp + 0,   *sh1 = (float*)auxp + 128;
    float* sc2 = (float*)auxp + 256, *sh2 = (float*)auxp + 384;
    float* sc3 = (float*)auxp + 512, *sh3 = (float*)auxp + 640;
    int*   bucketbase = (int*)(auxp + (768 + 64) * 4);
    int*   totals     = bucketbase + 300;
    int* rowptr = (int*)(auxp + aux_bytes);
    int* col    = rowptr + (nN + 1);

    // CSR-build scratch overlays B16 (dead until layer-1 output)
    unsigned* records = (unsigned*)B16;                       // nE*4 bytes
    int* blockhist    = (int*)((char*)B16 + (size_t)nE * 4);

    int nbuk = (nN + 511) >> SPANB;
    int nblk = (nE + CHUNK - 1) / CHUNK;
    long long n8 = (long long)nN * D / 8;
    int cvtBlocks = (int)((n8 + 255) / 256);

    // ---- mega prep: pack + bn + hist + cvt(x -> A16)
    prep_kernel<<<51 + nblk + cvtBlocks, 256, 0, stream>>>(
        w11, w12, w21, w22, w31, w32, Wp,
        bn1g, bn1b, bn1m, bn1v, b12,
        bn2g, bn2b, bn2m, bn2v, b22,
        bn3g, bn3b, bn3m, bn3v, b32,
        sc1, sh1, sc2, sh2, sc3, sh3,
        x, A16, n8,
        dstp, blockhist, nE, nblk);

    // ---- CSR build rest
    bscan_kernel<<<nbuk, 256, 0, stream>>>(blockhist, totals, nblk);
    tscan_kernel<<<1, 256, 0, stream>>>(totals, bucketbase, nbuk, nE);
    fill2_kernel<<<nblk, 256, 0, stream>>>(srcp, dstp, blockhist, bucketbase, records, nE, nbuk);
    csr2_kernel<<<nbuk, 512, 0, stream>>>(records, bucketbase, rowptr, col, nN, nE);

    int layerBlocks = (nN + 63) / 64;
    __hip_bfloat16* Wp1 = Wp + 0 * 16384; __hip_bfloat16* Wp2 = Wp + 1 * 16384;
    __hip_bfloat16* Wp3 = Wp + 2 * 16384; __hip_bfloat16* Wp4 = Wp + 3 * 16384;
    __hip_bfloat16* Wp5 = Wp + 4 * 16384; __hip_bfloat16* Wp6 = Wp + 5 * 16384;

    // ---- 3 fused layers, ping-pong A<->B
    layer_kernel<<<layerBlocks, 256, 0, stream>>>(A16, rowptr, col, Wp1, Wp2, b11, sc1, sh1, B16, nN);
    layer_kernel<<<layerBlocks, 256, 0, stream>>>(B16, rowptr, col, Wp3, Wp4, b21, sc2, sh2, A16, nN);
    layer_kernel<<<layerBlocks, 256, 0, stream>>>(A16, rowptr, col, Wp5, Wp6, b31, sc3, sh3, B16, nN);

    // ---- global mean pool: one block per graph
    pool2_kernel<<<nG, 1024, 0, stream>>>(B16, batch, (float*)d_out, nN);
}